// Round 11
// baseline (997.696 us; speedup 1.0000x reference)
//
#include <hip/hip_runtime.h>
#include <hip/hip_bf16.h>

#define H_DIM 2048
#define E_NUM 8
#define I_DIM 4096
#define TWO_I 8192
#define T_TOK 2048

#define BM 256
#define BN 64
#define BK 64

typedef __bf16 bf16x8 __attribute__((ext_vector_type(8)));
typedef float f32x4 __attribute__((ext_vector_type(4)));

static __device__ __forceinline__ unsigned short f2bs(float x) {
    __hip_bfloat16 h = __float2bfloat16(x);
    return __builtin_bit_cast(unsigned short, h);
}

#define GLL(gsrc, ldst) __builtin_amdgcn_global_load_lds( \
    (const __attribute__((address_space(1))) void*)(gsrc), \
    (__attribute__((address_space(3))) void*)(ldst), 16, 0, 0)

#define MFMA16(a, b, c) __builtin_amdgcn_mfma_f32_16x16x32_bf16(a, b, c, 0, 0, 0)
#define BSWZ(n) (((((n) & 7) ^ (((n) >> 2) & 7))) << 4)
#define A_SRC_CHUNK(lane) ((((lane) & 7) ^ (((lane) >> 3) & 7)) * 8)
// barrier WITHOUT vmcnt drain: LDS writes visible; global/GLL loads stay in flight
#define BARRIER() asm volatile("s_waitcnt lgkmcnt(0)\ns_barrier" ::: "memory")
// compiler-level fence: pins program order of memory ops (keeps vmcnt counts exact)
#define FENCE() asm volatile("" ::: "memory")

static __device__ __forceinline__ bf16x8 bload(
    const unsigned short* __restrict__ Bs, int n, int s, int h) {
    int off = (n * 128 + s * 64 + h * 16) ^ BSWZ(n);
    return *reinterpret_cast<const bf16x8*>((const char*)Bs + off);
}

static __device__ __forceinline__ bf16x8 aload(
    const unsigned short* __restrict__ As, int row, int s, int h) {
    int off = row * 128 + ((s * 64 + h * 16) ^ ((row & 7) << 4));
    return *reinterpret_cast<const bf16x8*>((const char*)As + off);
}

// ---------------- fused router + convert: one wave per token ----------------
__global__ __launch_bounds__(256) void router_convert_kernel(
    const float* __restrict__ hs, const float* __restrict__ rw,
    float* __restrict__ out_scores, int* __restrict__ eidx,
    unsigned short* __restrict__ xb, unsigned short* __restrict__ xs) {
    int tok = blockIdx.x * 4 + (threadIdx.x >> 6);
    int lane = threadIdx.x & 63;
    const float* row = hs + (size_t)tok * H_DIM;
    float4 v[8];
    float acc[E_NUM];
#pragma unroll
    for (int e = 0; e < E_NUM; e++) acc[e] = 0.f;
#pragma unroll
    for (int i = 0; i < 8; i++) {
        int hb = i * 256 + lane * 4;
        v[i] = *reinterpret_cast<const float4*>(row + hb);
        const float* w0 = rw + (size_t)hb * E_NUM;
#pragma unroll
        for (int e = 0; e < E_NUM; e++) {
            acc[e] += v[i].x * w0[e] + v[i].y * w0[E_NUM + e] +
                      v[i].z * w0[2 * E_NUM + e] + v[i].w * w0[3 * E_NUM + e];
        }
    }
#pragma unroll
    for (int e = 0; e < E_NUM; e++) {
#pragma unroll
        for (int o = 32; o > 0; o >>= 1) acc[e] += __shfl_xor(acc[e], o, 64);
    }
    int best = 0; float bv = acc[0];
#pragma unroll
    for (int e = 1; e < E_NUM; e++) { if (acc[e] > bv) { bv = acc[e]; best = e; } }
    float sc = 1.f / (1.f + expf(-bv));
    if (lane < E_NUM) out_scores[(size_t)lane * T_TOK + tok] = (lane == best) ? sc : 0.f;
    if (lane == 0) eidx[tok] = best;
    unsigned short* xbr = xb + (size_t)tok * H_DIM;
    unsigned short* xsr = xs + (size_t)tok * H_DIM;
#pragma unroll
    for (int i = 0; i < 8; i++) {
        int hb = i * 256 + lane * 4;
        ushort4 b, s4;
        b.x = f2bs(v[i].x); b.y = f2bs(v[i].y); b.z = f2bs(v[i].z); b.w = f2bs(v[i].w);
        s4.x = f2bs(v[i].x * sc); s4.y = f2bs(v[i].y * sc);
        s4.z = f2bs(v[i].z * sc); s4.w = f2bs(v[i].w * sc);
        *reinterpret_cast<ushort4*>(xbr + hb) = b;
        *reinterpret_cast<ushort4*>(xsr + hb) = s4;
    }
}

// ---------------- grouping ----------------
__global__ void group_kernel(const int* __restrict__ eidx, int* __restrict__ perm,
                             int* __restrict__ off) {
    __shared__ int cnt[E_NUM];
    __shared__ int base[E_NUM];
    int t = threadIdx.x;
    if (t < E_NUM) cnt[t] = 0;
    __syncthreads();
    for (int i = t; i < T_TOK; i += 256) atomicAdd(&cnt[eidx[i]], 1);
    __syncthreads();
    if (t == 0) {
        int s = 0;
        for (int e = 0; e < E_NUM; e++) { base[e] = s; off[e] = s; s += cnt[e]; }
        off[E_NUM] = s;
    }
    __syncthreads();
    for (int i = t; i < T_TOK; i += 256) {
        int e = eidx[i];
        int p = atomicAdd(&base[e], 1);
        perm[p] = i;
    }
}

// ---------------- GEMM1: R9 structure + q-depth-2 counted-vmcnt pipeline ----------------
// 256 thr, BM=256, BN=64 gate + 64 up, BK=64. As dbuf (GLL), B single-buf reg-staged.
// Steady state: iter t consumes q-set loaded at t-2; outstanding VMEM never < 12.
// grid.x = I/64, grid.y = g*8 + mt
__global__ __launch_bounds__(256, 2) void gemm1_kernel(
    const unsigned short* __restrict__ xb, const unsigned short* __restrict__ xs,
    const float* __restrict__ gup, const float* __restrict__ sg,
    const float* __restrict__ su, const int* __restrict__ perm,
    const int* __restrict__ off, unsigned short* __restrict__ hmid) {
    int nt = blockIdx.x;
    int g = blockIdx.y >> 3;
    int mt = blockIdx.y & 7;
    int rowbase, ng;
    if (g < E_NUM) { rowbase = off[g]; ng = off[g + 1] - rowbase; }
    else { rowbase = 0; ng = T_TOK; }
    int mstart = mt * BM;
    if (mstart >= ng) return;

    __shared__ unsigned short As[2][BM * BK];  // 2 x 32 KB
    __shared__ unsigned short LBg[BN * BK];    // 8 KB
    __shared__ unsigned short LBu[BN * BK];    // 8 KB

    int tid = threadIdx.x;
    int wave = tid >> 6, lane = tid & 63;
    int h = lane >> 4, ln = lane & 15;

    const unsigned short* Abase = (g == E_NUM) ? xb : xs;
    unsigned int aoff[8];
#pragma unroll
    for (int j = 0; j < 8; j++) {
        int r = wave * 64 + j * 8 + (lane >> 3);
        int sr = mstart + r; sr = (sr < ng) ? sr : (ng - 1);
        int tokr = (g < E_NUM) ? perm[rowbase + sr] : sr;
        aoff[j] = (unsigned int)tokr * H_DIM + A_SRC_CHUNK(lane);
    }
    int n0 = nt * BN;
    const float* gbase;
    const float* ubase;
    size_t ldb;
    if (g < E_NUM) {
        gbase = gup + (size_t)g * H_DIM * TWO_I + n0;
        ubase = gbase + I_DIM;
        ldb = TWO_I;
    } else {
        gbase = sg + n0;
        ubase = su + n0;
        ldb = I_DIM;
    }
    int k0i = wave * 16 + ((lane >> 4) << 2);  // 4 k-rows per lane
    int nb = (lane & 15) << 2;                 // 4 n-cols per lane
    const float* pg = gbase + (size_t)k0i * ldb + nb;
    const float* pu = ubase + (size_t)k0i * ldb + nb;

    f32x4 zero = {0.f, 0.f, 0.f, 0.f};
    f32x4 accg[4][4], accu[4][4];
#pragma unroll
    for (int i = 0; i < 4; i++)
#pragma unroll
        for (int j = 0; j < 4; j++) { accg[i][j] = zero; accu[i][j] = zero; }

    const int NT = H_DIM / BK;   // 32 (even)
    // two q register sets
    f32x4 qag0, qag1, qag2, qag3, qau0, qau1, qau2, qau3;
    f32x4 qbg0, qbg1, qbg2, qbg3, qbu0, qbu1, qbu2, qbu3;

#define G1_QLOAD(t_, G0,G1,G2,G3, U0,U1,U2,U3) { \
        size_t ko_ = (size_t)(t_) * BK * ldb; \
        const float* p_ = pg + ko_; \
        G0 = *reinterpret_cast<const f32x4*>(p_); \
        G1 = *reinterpret_cast<const f32x4*>(p_ + ldb); \
        G2 = *reinterpret_cast<const f32x4*>(p_ + 2 * ldb); \
        G3 = *reinterpret_cast<const f32x4*>(p_ + 3 * ldb); \
        p_ = pu + ko_; \
        U0 = *reinterpret_cast<const f32x4*>(p_); \
        U1 = *reinterpret_cast<const f32x4*>(p_ + ldb); \
        U2 = *reinterpret_cast<const f32x4*>(p_ + 2 * ldb); \
        U3 = *reinterpret_cast<const f32x4*>(p_ + 3 * ldb); }
#define G1_BWRITE(G0,G1,G2,G3, U0,U1,U2,U3) { _Pragma("unroll") \
        for (int i_ = 0; i_ < 4; i_++) { int n_ = nb + i_; \
            ushort4 og_, ou_; \
            og_.x = f2bs(G0[i_]); og_.y = f2bs(G1[i_]); \
            og_.z = f2bs(G2[i_]); og_.w = f2bs(G3[i_]); \
            ou_.x = f2bs(U0[i_]); ou_.y = f2bs(U1[i_]); \
            ou_.z = f2bs(U2[i_]); ou_.w = f2bs(U3[i_]); \
            int ob_ = (n_ * 128 + k0i * 2) ^ BSWZ(n_); \
            *reinterpret_cast<ushort4*>((char*)LBg + ob_) = og_; \
            *reinterpret_cast<ushort4*>((char*)LBu + ob_) = ou_; } }
#define G1_AGLL(t_, buf_) { _Pragma("unroll") \
        for (int j_ = 0; j_ < 8; j_++) \
            GLL(Abase + aoff[j_] + (unsigned)(t_) * BK, \
                &As[buf_][(wave * 64 + j_ * 8) * BK]); }
#define G1_COMPUTE(buf_) { const unsigned short* Ab_ = &As[buf_][0]; \
        _Pragma("unroll") \
        for (int s_ = 0; s_ < 2; s_++) { \
            bf16x8 a0_ = aload(Ab_, wave * 64 + 0 * 16 + ln, s_, h); \
            bf16x8 a1_ = aload(Ab_, wave * 64 + 1 * 16 + ln, s_, h); \
            bf16x8 a2_ = aload(Ab_, wave * 64 + 2 * 16 + ln, s_, h); \
            bf16x8 a3_ = aload(Ab_, wave * 64 + 3 * 16 + ln, s_, h); \
            _Pragma("unroll") \
            for (int j_ = 0; j_ < 4; j_++) { \
                bf16x8 wg_ = bload(LBg, j_ * 16 + ln, s_, h); \
                accg[0][j_] = MFMA16(a0_, wg_, accg[0][j_]); \
                accg[1][j_] = MFMA16(a1_, wg_, accg[1][j_]); \
                accg[2][j_] = MFMA16(a2_, wg_, accg[2][j_]); \
                accg[3][j_] = MFMA16(a3_, wg_, accg[3][j_]); \
            } \
            _Pragma("unroll") \
            for (int j_ = 0; j_ < 4; j_++) { \
                bf16x8 wu_ = bload(LBu, j_ * 16 + ln, s_, h); \
                accu[0][j_] = MFMA16(a0_, wu_, accu[0][j_]); \
                accu[1][j_] = MFMA16(a1_, wu_, accu[1][j_]); \
                accu[2][j_] = MFMA16(a2_, wu_, accu[2][j_]); \
                accu[3][j_] = MFMA16(a3_, wu_, accu[3][j_]); \
            } \
        } }
// one segment: compute tile t from As[buf_], then refill B(t+1) / A(t+2) / q(t+3)
#define G1_SEG(t_, buf_, G0,G1,G2,G3, U0,U1,U2,U3) { \
        asm volatile("s_waitcnt vmcnt(20)" ::: "memory"); \
        G1_COMPUTE(buf_); \
        BARRIER(); \
        G1_BWRITE(G0,G1,G2,G3, U0,U1,U2,U3); \
        FENCE(); \
        { int tc_ = (t_) + 2; if (tc_ > NT - 1) tc_ = NT - 1; G1_AGLL(tc_, buf_); } \
        FENCE(); \
        { int tq_ = (t_) + 3; if (tq_ > NT - 1) tq_ = NT - 1; \
          G1_QLOAD(tq_, G0,G1,G2,G3, U0,U1,U2,U3); } \
        BARRIER(); }

    // prologue: establish steady-state in-flight set (24 outstanding)
    G1_QLOAD(0, qag0,qag1,qag2,qag3, qau0,qau1,qau2,qau3);
    G1_AGLL(0, 0);
    FENCE();
    G1_BWRITE(qag0,qag1,qag2,qag3, qau0,qau1,qau2,qau3);  // implicit wait leaves GLL A0
    FENCE();
    G1_AGLL(1, 1);
    FENCE();
    G1_QLOAD(1, qag0,qag1,qag2,qag3, qau0,qau1,qau2,qau3);
    G1_QLOAD(2, qbg0,qbg1,qbg2,qbg3, qbu0,qbu1,qbu2,qbu3);
    BARRIER();

    for (int t = 0; t < NT; t += 2) {
        G1_SEG(t,     0, qag0,qag1,qag2,qag3, qau0,qau1,qau2,qau3)
        G1_SEG(t + 1, 1, qbg0,qbg1,qbg2,qbg3, qbu0,qbu1,qbu2,qbu3)
    }

    int hbase = (g < E_NUM) ? rowbase : T_TOK;
#pragma unroll
    for (int i = 0; i < 4; i++) {
#pragma unroll
        for (int j = 0; j < 4; j++) {
#pragma unroll
            for (int r = 0; r < 4; r++) {
                int row = wave * 64 + i * 16 + h * 4 + r;
                int sr = mstart + row;
                if (sr < ng) {
                    float gv = accg[i][j][r], uv = accu[i][j][r];
                    float hv = gv / (1.f + expf(-gv)) * uv;  // silu(g)*u
                    int col = n0 + j * 16 + ln;
                    hmid[(size_t)(hbase + sr) * I_DIM + col] = f2bs(hv);
                }
            }
        }
    }
}

// ---------------- GEMM2: same pipeline. ADD=0 shared writes, ADD=1 routed += ----------
// 256 thr, BM=256, BN=64, BK=64. grid.x = H/64. ADD=0: grid.y=mt(0..7); ADD=1: g*8+mt
template <int ADD>
__global__ __launch_bounds__(256, 2) void gemm2_kernel(
    const unsigned short* __restrict__ hmid, const float* __restrict__ dwn,
    const float* __restrict__ sd, const int* __restrict__ perm,
    const int* __restrict__ off, float* __restrict__ out) {
    int nt = blockIdx.x;
    int g, mt, rowbase, ng, hbase;
    if (ADD) {
        g = blockIdx.y >> 3; mt = blockIdx.y & 7;
        rowbase = off[g]; ng = off[g + 1] - rowbase; hbase = rowbase;
    } else {
        g = E_NUM; mt = blockIdx.y; rowbase = 0; ng = T_TOK; hbase = T_TOK;
    }
    int mstart = mt * BM;
    if (mstart >= ng) return;

    __shared__ unsigned short As[2][BM * BK];  // 2 x 32 KB
    __shared__ unsigned short LBs[BN * BK];    // 8 KB

    int tid = threadIdx.x;
    int wave = tid >> 6, lane = tid & 63;
    int h = lane >> 4, ln = lane & 15;

    unsigned int aoff[8];
#pragma unroll
    for (int j = 0; j < 8; j++) {
        int r = wave * 64 + j * 8 + (lane >> 3);
        int sr = mstart + r; sr = (sr < ng) ? sr : (ng - 1);
        aoff[j] = (unsigned int)(hbase + sr) * I_DIM + A_SRC_CHUNK(lane);
    }
    int n0 = nt * BN;
    const float* bbase = ADD ? (dwn + (size_t)g * I_DIM * H_DIM + n0) : (sd + n0);
    const size_t ldb = H_DIM;
    int k0i = wave * 16 + ((lane >> 4) << 2);
    int nb = (lane & 15) << 2;
    const float* pb = bbase + (size_t)k0i * ldb + nb;

    f32x4 zero = {0.f, 0.f, 0.f, 0.f};
    f32x4 acc[4][4];
#pragma unroll
    for (int i = 0; i < 4; i++)
#pragma unroll
        for (int j = 0; j < 4; j++) acc[i][j] = zero;

    const int NT2 = I_DIM / BK;  // 64 (even)
    f32x4 qa0, qa1, qa2, qa3, qb0, qb1, qb2, qb3;

#define G2_QLOAD(t_, Q0,Q1,Q2,Q3) { size_t ko_ = (size_t)(t_) * BK * ldb; \
        const float* p_ = pb + ko_; \
        Q0 = *reinterpret_cast<const f32x4*>(p_); \
        Q1 = *reinterpret_cast<const f32x4*>(p_ + ldb); \
        Q2 = *reinterpret_cast<const f32x4*>(p_ + 2 * ldb); \
        Q3 = *reinterpret_cast<const f32x4*>(p_ + 3 * ldb); }
#define G2_BWRITE(Q0,Q1,Q2,Q3) { _Pragma("unroll") \
        for (int i_ = 0; i_ < 4; i_++) { int n_ = nb + i_; \
            ushort4 o_; \
            o_.x = f2bs(Q0[i_]); o_.y = f2bs(Q1[i_]); \
            o_.z = f2bs(Q2[i_]); o_.w = f2bs(Q3[i_]); \
            int ob_ = (n_ * 128 + k0i * 2) ^ BSWZ(n_); \
            *reinterpret_cast<ushort4*>((char*)LBs + ob_) = o_; } }
#define G2_AGLL(t_, buf_) { _Pragma("unroll") \
        for (int j_ = 0; j_ < 8; j_++) \
            GLL(hmid + aoff[j_] + (unsigned)(t_) * BK, \
                &As[buf_][(wave * 64 + j_ * 8) * BK]); }
#define G2_COMPUTE(buf_) { const unsigned short* Ab_ = &As[buf_][0]; \
        _Pragma("unroll") \
        for (int s_ = 0; s_ < 2; s_++) { \
            bf16x8 a0_ = aload(Ab_, wave * 64 + 0 * 16 + ln, s_, h); \
            bf16x8 a1_ = aload(Ab_, wave * 64 + 1 * 16 + ln, s_, h); \
            bf16x8 a2_ = aload(Ab_, wave * 64 + 2 * 16 + ln, s_, h); \
            bf16x8 a3_ = aload(Ab_, wave * 64 + 3 * 16 + ln, s_, h); \
            _Pragma("unroll") \
            for (int j_ = 0; j_ < 4; j_++) { \
                bf16x8 wb_ = bload(LBs, j_ * 16 + ln, s_, h); \
                acc[0][j_] = MFMA16(a0_, wb_, acc[0][j_]); \
                acc[1][j_] = MFMA16(a1_, wb_, acc[1][j_]); \
                acc[2][j_] = MFMA16(a2_, wb_, acc[2][j_]); \
                acc[3][j_] = MFMA16(a3_, wb_, acc[3][j_]); \
            } \
        } }
#define G2_SEG(t_, buf_, Q0,Q1,Q2,Q3) { \
        asm volatile("s_waitcnt vmcnt(16)" ::: "memory"); \
        G2_COMPUTE(buf_); \
        BARRIER(); \
        G2_BWRITE(Q0,Q1,Q2,Q3); \
        FENCE(); \
        { int tc_ = (t_) + 2; if (tc_ > NT2 - 1) tc_ = NT2 - 1; G2_AGLL(tc_, buf_); } \
        FENCE(); \
        { int tq_ = (t_) + 3; if (tq_ > NT2 - 1) tq_ = NT2 - 1; \
          G2_QLOAD(tq_, Q0,Q1,Q2,Q3); } \
        BARRIER(); }

    G2_QLOAD(0, qa0,qa1,qa2,qa3);
    G2_AGLL(0, 0);
    FENCE();
    G2_BWRITE(qa0,qa1,qa2,qa3);
    FENCE();
    G2_AGLL(1, 1);
    FENCE();
    G2_QLOAD(1, qa0,qa1,qa2,qa3);
    G2_QLOAD(2, qb0,qb1,qb2,qb3);
    BARRIER();

    for (int t = 0; t < NT2; t += 2) {
        G2_SEG(t,     0, qa0,qa1,qa2,qa3)
        G2_SEG(t + 1, 1, qb0,qb1,qb2,qb3)
    }

#pragma unroll
    for (int i = 0; i < 4; i++) {
#pragma unroll
        for (int j = 0; j < 4; j++) {
#pragma unroll
            for (int r = 0; r < 4; r++) {
                int row = wave * 64 + i * 16 + h * 4 + r;
                int sr = mstart + row;
                if (sr < ng) {
                    int tok = ADD ? perm[rowbase + sr] : sr;
                    int col = n0 + j * 16 + ln;
                    float v = acc[i][j][r];
                    float* o = out + (size_t)tok * H_DIM + col;
                    if (ADD) *o += v; else *o = v;
                }
            }
        }
    }
}

extern "C" void kernel_launch(void* const* d_in, const int* in_sizes, int n_in,
                              void* d_out, int out_size, void* d_ws, size_t ws_size,
                              hipStream_t stream) {
    (void)in_sizes; (void)n_in; (void)out_size;
    const float* hs  = (const float*)d_in[0];
    const float* rw  = (const float*)d_in[1];
    const float* gup = (const float*)d_in[2];
    const float* dwn = (const float*)d_in[3];
    const float* sg  = (const float*)d_in[4];
    const float* su  = (const float*)d_in[5];
    const float* sd  = (const float*)d_in[6];
    float* out = (float*)d_out;
    float* out_scores = out + (size_t)T_TOK * H_DIM;

    char* w = (char*)d_ws;
    size_t o = 0;
    auto alloc = [&](size_t bytes) {
        void* p = w + o;
        o += (bytes + 255) & ~(size_t)255;
        return p;
    };
    unsigned short* xb   = (unsigned short*)alloc((size_t)T_TOK * H_DIM * 2);
    unsigned short* xs   = (unsigned short*)alloc((size_t)T_TOK * H_DIM * 2);
    unsigned short* hmid = (unsigned short*)alloc((size_t)2 * T_TOK * I_DIM * 2);
    int* eidx    = (int*)alloc(T_TOK * 4);
    int* perm    = (int*)alloc(T_TOK * 4);
    int* off     = (int*)alloc(64 * 4);
    if (ws_size < o) return;  // insufficient workspace

    router_convert_kernel<<<T_TOK / 4, 256, 0, stream>>>(hs, rw, out_scores, eidx, xb, xs);
    group_kernel<<<1, 256, 0, stream>>>(eidx, perm, off);

    gemm1_kernel<<<dim3(I_DIM / BN, 9 * 8), 256, 0, stream>>>(
        xb, xs, gup, sg, su, perm, off, hmid);
    gemm2_kernel<0><<<dim3(H_DIM / BN, 8), 256, 0, stream>>>(hmid, dwn, sd, perm, off, out);
    gemm2_kernel<1><<<dim3(H_DIM / BN, E_NUM * 8), 256, 0, stream>>>(hmid, dwn, sd, perm, off, out);
}

// Round 12
// 753.225 us; speedup vs baseline: 1.3246x; 1.3246x over previous
//
#include <hip/hip_runtime.h>
#include <hip/hip_bf16.h>

#define H_DIM 2048
#define E_NUM 8
#define I_DIM 4096
#define TWO_I 8192
#define T_TOK 2048

#define BM 256
#define BN 32
#define BK 32

typedef __bf16 bf16x8 __attribute__((ext_vector_type(8)));
typedef float f32x4 __attribute__((ext_vector_type(4)));
typedef float f32x2 __attribute__((ext_vector_type(2)));

static __device__ __forceinline__ unsigned short f2bs(float x) {
    __hip_bfloat16 h = __float2bfloat16(x);
    return __builtin_bit_cast(unsigned short, h);
}

#define GLL(gsrc, ldst) __builtin_amdgcn_global_load_lds( \
    (const __attribute__((address_space(1))) void*)(gsrc), \
    (__attribute__((address_space(3))) void*)(ldst), 16, 0, 0)

#define MFMA16(a, b, c) __builtin_amdgcn_mfma_f32_16x16x32_bf16(a, b, c, 0, 0, 0)
// 64B-row swizzle (BK=32 bf16 rows): phys 16B-chunk = logical ^ ((row&3)^((row>>2)&3))
#define SWZ3(r) (((r) & 3) ^ (((r) >> 2) & 3))
// GLL source chunk for lane l (row = base + (l>>2), phys chunk = l&3)
#define A_SRC_CHUNK(l) ((((l) & 3) ^ (((l) >> 2) & 3) ^ (((l) >> 4) & 3)) * 8)
// barrier WITHOUT vmcnt drain: LDS writes visible; global/GLL loads stay in flight
#define BARRIER() asm volatile("s_waitcnt lgkmcnt(0)\ns_barrier" ::: "memory")

static __device__ __forceinline__ bf16x8 tload(
    const unsigned short* __restrict__ T, int row, int h) {
    int off = row * 64 + ((h * 16) ^ (SWZ3(row) << 4));
    return *reinterpret_cast<const bf16x8*>((const char*)T + off);
}

// ---------------- fused router + convert: one wave per token ----------------
__global__ __launch_bounds__(256) void router_convert_kernel(
    const float* __restrict__ hs, const float* __restrict__ rw,
    float* __restrict__ out_scores, int* __restrict__ eidx,
    unsigned short* __restrict__ xb, unsigned short* __restrict__ xs) {
    int tok = blockIdx.x * 4 + (threadIdx.x >> 6);
    int lane = threadIdx.x & 63;
    const float* row = hs + (size_t)tok * H_DIM;
    float4 v[8];
    float acc[E_NUM];
#pragma unroll
    for (int e = 0; e < E_NUM; e++) acc[e] = 0.f;
#pragma unroll
    for (int i = 0; i < 8; i++) {
        int hb = i * 256 + lane * 4;
        v[i] = *reinterpret_cast<const float4*>(row + hb);
        const float* w0 = rw + (size_t)hb * E_NUM;
#pragma unroll
        for (int e = 0; e < E_NUM; e++) {
            acc[e] += v[i].x * w0[e] + v[i].y * w0[E_NUM + e] +
                      v[i].z * w0[2 * E_NUM + e] + v[i].w * w0[3 * E_NUM + e];
        }
    }
#pragma unroll
    for (int e = 0; e < E_NUM; e++) {
#pragma unroll
        for (int o = 32; o > 0; o >>= 1) acc[e] += __shfl_xor(acc[e], o, 64);
    }
    int best = 0; float bv = acc[0];
#pragma unroll
    for (int e = 1; e < E_NUM; e++) { if (acc[e] > bv) { bv = acc[e]; best = e; } }
    float sc = 1.f / (1.f + expf(-bv));
    if (lane < E_NUM) out_scores[(size_t)lane * T_TOK + tok] = (lane == best) ? sc : 0.f;
    if (lane == 0) eidx[tok] = best;
    unsigned short* xbr = xb + (size_t)tok * H_DIM;
    unsigned short* xsr = xs + (size_t)tok * H_DIM;
#pragma unroll
    for (int i = 0; i < 8; i++) {
        int hb = i * 256 + lane * 4;
        ushort4 b, s4;
        b.x = f2bs(v[i].x); b.y = f2bs(v[i].y); b.z = f2bs(v[i].z); b.w = f2bs(v[i].w);
        s4.x = f2bs(v[i].x * sc); s4.y = f2bs(v[i].y * sc);
        s4.z = f2bs(v[i].z * sc); s4.w = f2bs(v[i].w * sc);
        *reinterpret_cast<ushort4*>(xbr + hb) = b;
        *reinterpret_cast<ushort4*>(xsr + hb) = s4;
    }
}

// ---------------- grouping ----------------
__global__ void group_kernel(const int* __restrict__ eidx, int* __restrict__ perm,
                             int* __restrict__ off) {
    __shared__ int cnt[E_NUM];
    __shared__ int base[E_NUM];
    int t = threadIdx.x;
    if (t < E_NUM) cnt[t] = 0;
    __syncthreads();
    for (int i = t; i < T_TOK; i += 256) atomicAdd(&cnt[eidx[i]], 1);
    __syncthreads();
    if (t == 0) {
        int s = 0;
        for (int e = 0; e < E_NUM; e++) { base[e] = s; off[e] = s; s += cnt[e]; }
        off[E_NUM] = s;
    }
    __syncthreads();
    for (int i = t; i < T_TOK; i += 256) {
        int e = eidx[i];
        int p = atomicAdd(&base[e], 1);
        perm[p] = i;
    }
}

// ---------------- GEMM1: R9 schedule, BK=32/BN=32, 3 blocks/CU ----------------
// 256 thr, BM=256, 32 gate + 32 up cols, BK=32. As dbuf (GLL), B single-buf reg-staged.
// grid.x = I/32 (128), grid.y = g*8 + mt
__global__ __launch_bounds__(256, 3) void gemm1_kernel(
    const unsigned short* __restrict__ xb, const unsigned short* __restrict__ xs,
    const float* __restrict__ gup, const float* __restrict__ sg,
    const float* __restrict__ su, const int* __restrict__ perm,
    const int* __restrict__ off, unsigned short* __restrict__ hmid) {
    int nt = blockIdx.x;
    int g = blockIdx.y >> 3;
    int mt = blockIdx.y & 7;
    int rowbase, ng;
    if (g < E_NUM) { rowbase = off[g]; ng = off[g + 1] - rowbase; }
    else { rowbase = 0; ng = T_TOK; }
    int mstart = mt * BM;
    if (mstart >= ng) return;

    __shared__ unsigned short As[2][BM * BK];  // 2 x 16 KB
    __shared__ unsigned short Bg[BN * BK];     // 2 KB
    __shared__ unsigned short Bu[BN * BK];     // 2 KB

    int tid = threadIdx.x;
    int wave = tid >> 6, lane = tid & 63;
    int h = lane >> 4, ln = lane & 15;

    const unsigned short* Abase = (g == E_NUM) ? xb : xs;
    unsigned int aoff[4];
#pragma unroll
    for (int j = 0; j < 4; j++) {
        int r = wave * 64 + j * 16 + (lane >> 2);
        int sr = mstart + r; sr = (sr < ng) ? sr : (ng - 1);
        int tokr = (g < E_NUM) ? perm[rowbase + sr] : sr;
        aoff[j] = (unsigned int)tokr * H_DIM + A_SRC_CHUNK(lane);
    }
    int n0 = nt * BN;
    const float* gbase;
    const float* ubase;
    size_t ldb;
    if (g < E_NUM) {
        gbase = gup + (size_t)g * H_DIM * TWO_I + n0;
        ubase = gbase + I_DIM;
        ldb = TWO_I;
    } else {
        gbase = sg + n0;
        ubase = su + n0;
        ldb = I_DIM;
    }
    int nb = (tid & 15) * 2;   // 2 n-cols per thread
    int kk = (tid >> 4) * 2;   // 2 k-rows per thread
    const float* pg = gbase + (size_t)kk * ldb + nb;
    const float* pu = ubase + (size_t)kk * ldb + nb;

    f32x4 zero = {0.f, 0.f, 0.f, 0.f};
    f32x4 accg[4][2], accu[4][2];
#pragma unroll
    for (int i = 0; i < 4; i++)
#pragma unroll
        for (int j = 0; j < 2; j++) { accg[i][j] = zero; accu[i][j] = zero; }

    const int NT = H_DIM / BK;   // 64
    f32x2 qg0, qg1, qu0, qu1;    // q regs: 2 rows x 2 cols per matrix

#define G1_QLOAD(t_) { size_t ko_ = (size_t)(t_) * BK * ldb; \
        qg0 = *reinterpret_cast<const f32x2*>(pg + ko_); \
        qg1 = *reinterpret_cast<const f32x2*>(pg + ko_ + ldb); \
        qu0 = *reinterpret_cast<const f32x2*>(pu + ko_); \
        qu1 = *reinterpret_cast<const f32x2*>(pu + ko_ + ldb); }
#define G1_BWRITE() { _Pragma("unroll") \
        for (int i_ = 0; i_ < 2; i_++) { int n_ = nb + i_; \
            unsigned og_ = (unsigned)f2bs(qg0[i_]) | ((unsigned)f2bs(qg1[i_]) << 16); \
            unsigned ou_ = (unsigned)f2bs(qu0[i_]) | ((unsigned)f2bs(qu1[i_]) << 16); \
            int ob_ = (n_ * 64 + kk * 2) ^ (SWZ3(n_) << 4); \
            *reinterpret_cast<unsigned*>((char*)Bg + ob_) = og_; \
            *reinterpret_cast<unsigned*>((char*)Bu + ob_) = ou_; } }
#define G1_AGLL(t_, buf_) { _Pragma("unroll") \
        for (int j_ = 0; j_ < 4; j_++) \
            GLL(Abase + aoff[j_] + (unsigned)(t_) * BK, \
                &As[buf_][(wave * 64 + j_ * 16) * BK]); }

    // prologue: B(0)->LDS, A(0)->As[0], A(1)->As[1], B(1)->regs
    G1_QLOAD(0);
    G1_AGLL(0, 0);
    asm volatile("s_waitcnt vmcnt(0)" ::: "memory");
    G1_BWRITE();
    G1_AGLL(1, 1);
    G1_QLOAD(1);
    BARRIER();

    for (int t = 0; t < NT; ++t) {
        const unsigned short* Ab = &As[t & 1][0];
        {
            bf16x8 a0 = tload(Ab, wave * 64 + 0 * 16 + ln, h);
            bf16x8 a1 = tload(Ab, wave * 64 + 1 * 16 + ln, h);
            bf16x8 a2 = tload(Ab, wave * 64 + 2 * 16 + ln, h);
            bf16x8 a3 = tload(Ab, wave * 64 + 3 * 16 + ln, h);
#pragma unroll
            for (int j = 0; j < 2; j++) {
                bf16x8 bg = tload(Bg, j * 16 + ln, h);
                accg[0][j] = MFMA16(a0, bg, accg[0][j]);
                accg[1][j] = MFMA16(a1, bg, accg[1][j]);
                accg[2][j] = MFMA16(a2, bg, accg[2][j]);
                accg[3][j] = MFMA16(a3, bg, accg[3][j]);
            }
#pragma unroll
            for (int j = 0; j < 2; j++) {
                bf16x8 bu = tload(Bu, j * 16 + ln, h);
                accu[0][j] = MFMA16(a0, bu, accu[0][j]);
                accu[1][j] = MFMA16(a1, bu, accu[1][j]);
                accu[2][j] = MFMA16(a2, bu, accu[2][j]);
                accu[3][j] = MFMA16(a3, bu, accu[3][j]);
            }
        }
        BARRIER();                       // reads of As[t&1], B(t) done
        if (t + 1 < NT) {
            G1_BWRITE();                 // B(t+1); implicit counted vmcnt here only
            int tc = t + 2; if (tc > NT - 1) tc = NT - 1;
            G1_AGLL(tc, t & 1);          // A(t+2) into the buffer just read
            G1_QLOAD(tc);                // B(t+2) -> regs, stays in flight
            BARRIER();                   // B(t+1) visible; loads NOT drained
        }
    }

    int hbase = (g < E_NUM) ? rowbase : T_TOK;
#pragma unroll
    for (int i = 0; i < 4; i++) {
#pragma unroll
        for (int j = 0; j < 2; j++) {
#pragma unroll
            for (int r = 0; r < 4; r++) {
                int row = wave * 64 + i * 16 + h * 4 + r;
                int sr = mstart + row;
                if (sr < ng) {
                    float gv = accg[i][j][r], uv = accu[i][j][r];
                    float hv = gv / (1.f + expf(-gv)) * uv;  // silu(g)*u
                    int col = n0 + j * 16 + ln;
                    hmid[(size_t)(hbase + sr) * I_DIM + col] = f2bs(hv);
                }
            }
        }
    }
}

// ---------------- GEMM2: down proj, same pipeline, BK=32/BN=32 ----------------
// 256 thr, BM=256, BN=32, BK=32. grid.x = H/32. ADD=0: grid.y=mt(0..7); ADD=1: g*8+mt
template <int ADD>
__global__ __launch_bounds__(256, 3) void gemm2_kernel(
    const unsigned short* __restrict__ hmid, const float* __restrict__ dwn,
    const float* __restrict__ sd, const int* __restrict__ perm,
    const int* __restrict__ off, float* __restrict__ out) {
    int nt = blockIdx.x;
    int g, mt, rowbase, ng, hbase;
    if (ADD) {
        g = blockIdx.y >> 3; mt = blockIdx.y & 7;
        rowbase = off[g]; ng = off[g + 1] - rowbase; hbase = rowbase;
    } else {
        g = E_NUM; mt = blockIdx.y; rowbase = 0; ng = T_TOK; hbase = T_TOK;
    }
    int mstart = mt * BM;
    if (mstart >= ng) return;

    __shared__ unsigned short As[2][BM * BK];  // 2 x 16 KB
    __shared__ unsigned short Bs[BN * BK];     // 2 KB

    int tid = threadIdx.x;
    int wave = tid >> 6, lane = tid & 63;
    int h = lane >> 4, ln = lane & 15;

    unsigned int aoff[4];
#pragma unroll
    for (int j = 0; j < 4; j++) {
        int r = wave * 64 + j * 16 + (lane >> 2);
        int sr = mstart + r; sr = (sr < ng) ? sr : (ng - 1);
        aoff[j] = (unsigned int)(hbase + sr) * I_DIM + A_SRC_CHUNK(lane);
    }
    int n0 = nt * BN;
    const float* bbase = ADD ? (dwn + (size_t)g * I_DIM * H_DIM + n0) : (sd + n0);
    const size_t ldb = H_DIM;
    int nb = (tid & 15) * 2;
    int kk = (tid >> 4) * 2;
    const float* pb = bbase + (size_t)kk * ldb + nb;

    f32x4 zero = {0.f, 0.f, 0.f, 0.f};
    f32x4 acc[4][2];
#pragma unroll
    for (int i = 0; i < 4; i++)
#pragma unroll
        for (int j = 0; j < 2; j++) acc[i][j] = zero;

    const int NT2 = I_DIM / BK;  // 128
    f32x2 qb0, qb1;

#define G2_QLOAD(t_) { size_t ko_ = (size_t)(t_) * BK * ldb; \
        qb0 = *reinterpret_cast<const f32x2*>(pb + ko_); \
        qb1 = *reinterpret_cast<const f32x2*>(pb + ko_ + ldb); }
#define G2_BWRITE() { _Pragma("unroll") \
        for (int i_ = 0; i_ < 2; i_++) { int n_ = nb + i_; \
            unsigned o_ = (unsigned)f2bs(qb0[i_]) | ((unsigned)f2bs(qb1[i_]) << 16); \
            int ob_ = (n_ * 64 + kk * 2) ^ (SWZ3(n_) << 4); \
            *reinterpret_cast<unsigned*>((char*)Bs + ob_) = o_; } }
#define G2_AGLL(t_, buf_) { _Pragma("unroll") \
        for (int j_ = 0; j_ < 4; j_++) \
            GLL(hmid + aoff[j_] + (unsigned)(t_) * BK, \
                &As[buf_][(wave * 64 + j_ * 16) * BK]); }

    G2_QLOAD(0);
    G2_AGLL(0, 0);
    asm volatile("s_waitcnt vmcnt(0)" ::: "memory");
    G2_BWRITE();
    G2_AGLL(1, 1);
    G2_QLOAD(1);
    BARRIER();

    for (int t = 0; t < NT2; ++t) {
        const unsigned short* Ab = &As[t & 1][0];
        {
            bf16x8 a0 = tload(Ab, wave * 64 + 0 * 16 + ln, h);
            bf16x8 a1 = tload(Ab, wave * 64 + 1 * 16 + ln, h);
            bf16x8 a2 = tload(Ab, wave * 64 + 2 * 16 + ln, h);
            bf16x8 a3 = tload(Ab, wave * 64 + 3 * 16 + ln, h);
#pragma unroll
            for (int j = 0; j < 2; j++) {
                bf16x8 b = tload(Bs, j * 16 + ln, h);
                acc[0][j] = MFMA16(a0, b, acc[0][j]);
                acc[1][j] = MFMA16(a1, b, acc[1][j]);
                acc[2][j] = MFMA16(a2, b, acc[2][j]);
                acc[3][j] = MFMA16(a3, b, acc[3][j]);
            }
        }
        BARRIER();
        if (t + 1 < NT2) {
            G2_BWRITE();
            int tc = t + 2; if (tc > NT2 - 1) tc = NT2 - 1;
            G2_AGLL(tc, t & 1);
            G2_QLOAD(tc);
            BARRIER();
        }
    }

#pragma unroll
    for (int i = 0; i < 4; i++) {
#pragma unroll
        for (int j = 0; j < 2; j++) {
#pragma unroll
            for (int r = 0; r < 4; r++) {
                int row = wave * 64 + i * 16 + h * 4 + r;
                int sr = mstart + row;
                if (sr < ng) {
                    int tok = ADD ? perm[rowbase + sr] : sr;
                    int col = n0 + j * 16 + ln;
                    float v = acc[i][j][r];
                    float* o = out + (size_t)tok * H_DIM + col;
                    if (ADD) *o += v; else *o = v;
                }
            }
        }
    }
}

extern "C" void kernel_launch(void* const* d_in, const int* in_sizes, int n_in,
                              void* d_out, int out_size, void* d_ws, size_t ws_size,
                              hipStream_t stream) {
    (void)in_sizes; (void)n_in; (void)out_size;
    const float* hs  = (const float*)d_in[0];
    const float* rw  = (const float*)d_in[1];
    const float* gup = (const float*)d_in[2];
    const float* dwn = (const float*)d_in[3];
    const float* sg  = (const float*)d_in[4];
    const float* su  = (const float*)d_in[5];
    const float* sd  = (const float*)d_in[6];
    float* out = (float*)d_out;
    float* out_scores = out + (size_t)T_TOK * H_DIM;

    char* w = (char*)d_ws;
    size_t o = 0;
    auto alloc = [&](size_t bytes) {
        void* p = w + o;
        o += (bytes + 255) & ~(size_t)255;
        return p;
    };
    unsigned short* xb   = (unsigned short*)alloc((size_t)T_TOK * H_DIM * 2);
    unsigned short* xs   = (unsigned short*)alloc((size_t)T_TOK * H_DIM * 2);
    unsigned short* hmid = (unsigned short*)alloc((size_t)2 * T_TOK * I_DIM * 2);
    int* eidx    = (int*)alloc(T_TOK * 4);
    int* perm    = (int*)alloc(T_TOK * 4);
    int* off     = (int*)alloc(64 * 4);
    if (ws_size < o) return;  // insufficient workspace

    router_convert_kernel<<<T_TOK / 4, 256, 0, stream>>>(hs, rw, out_scores, eidx, xb, xs);
    group_kernel<<<1, 256, 0, stream>>>(eidx, perm, off);

    gemm1_kernel<<<dim3(I_DIM / BN, 9 * 8), 256, 0, stream>>>(
        xb, xs, gup, sg, su, perm, off, hmid);
    gemm2_kernel<0><<<dim3(H_DIM / BN, 8), 256, 0, stream>>>(hmid, dwn, sd, perm, off, out);
    gemm2_kernel<1><<<dim3(H_DIM / BN, E_NUM * 8), 256, 0, stream>>>(hmid, dwn, sd, perm, off, out);
}

// Round 13
// 613.697 us; speedup vs baseline: 1.6257x; 1.2274x over previous
//
#include <hip/hip_runtime.h>
#include <hip/hip_bf16.h>

#define H_DIM 2048
#define E_NUM 8
#define I_DIM 4096
#define TWO_I 8192
#define T_TOK 2048

#define BM 256
#define BN 32
#define BK 64

typedef __bf16 bf16x8 __attribute__((ext_vector_type(8)));
typedef float f32x4 __attribute__((ext_vector_type(4)));

static __device__ __forceinline__ unsigned short f2bs(float x) {
    __hip_bfloat16 h = __float2bfloat16(x);
    return __builtin_bit_cast(unsigned short, h);
}

#define GLL(gsrc, ldst) __builtin_amdgcn_global_load_lds( \
    (const __attribute__((address_space(1))) void*)(gsrc), \
    (__attribute__((address_space(3))) void*)(ldst), 16, 0, 0)

#define MFMA16(a, b, c) __builtin_amdgcn_mfma_f32_16x16x32_bf16(a, b, c, 0, 0, 0)
#define BSWZ(n) (((((n) & 7) ^ (((n) >> 2) & 7))) << 4)
#define A_SRC_CHUNK(lane) ((((lane) & 7) ^ (((lane) >> 3) & 7)) * 8)
// barrier WITHOUT vmcnt drain: LDS writes visible; global/GLL loads stay in flight
#define BARRIER() asm volatile("s_waitcnt lgkmcnt(0)\ns_barrier" ::: "memory")
// compiler-order fence (free at runtime): pins VMEM issue order so counted waits stay exact
#define FENCE() asm volatile("" ::: "memory")

static __device__ __forceinline__ bf16x8 bload(
    const unsigned short* __restrict__ Bs, int n, int s, int h) {
    int off = (n * 128 + s * 64 + h * 16) ^ BSWZ(n);
    return *reinterpret_cast<const bf16x8*>((const char*)Bs + off);
}

static __device__ __forceinline__ bf16x8 aload(
    const unsigned short* __restrict__ As, int row, int s, int h) {
    int off = row * 128 + ((s * 64 + h * 16) ^ ((row & 7) << 4));
    return *reinterpret_cast<const bf16x8*>((const char*)As + off);
}

// ---------------- fused router + convert: one wave per token ----------------
__global__ __launch_bounds__(256) void router_convert_kernel(
    const float* __restrict__ hs, const float* __restrict__ rw,
    float* __restrict__ out_scores, int* __restrict__ eidx,
    unsigned short* __restrict__ xb, unsigned short* __restrict__ xs) {
    int tok = blockIdx.x * 4 + (threadIdx.x >> 6);
    int lane = threadIdx.x & 63;
    const float* row = hs + (size_t)tok * H_DIM;
    float4 v[8];
    float acc[E_NUM];
#pragma unroll
    for (int e = 0; e < E_NUM; e++) acc[e] = 0.f;
#pragma unroll
    for (int i = 0; i < 8; i++) {
        int hb = i * 256 + lane * 4;
        v[i] = *reinterpret_cast<const float4*>(row + hb);
        const float* w0 = rw + (size_t)hb * E_NUM;
#pragma unroll
        for (int e = 0; e < E_NUM; e++) {
            acc[e] += v[i].x * w0[e] + v[i].y * w0[E_NUM + e] +
                      v[i].z * w0[2 * E_NUM + e] + v[i].w * w0[3 * E_NUM + e];
        }
    }
#pragma unroll
    for (int e = 0; e < E_NUM; e++) {
#pragma unroll
        for (int o = 32; o > 0; o >>= 1) acc[e] += __shfl_xor(acc[e], o, 64);
    }
    int best = 0; float bv = acc[0];
#pragma unroll
    for (int e = 1; e < E_NUM; e++) { if (acc[e] > bv) { bv = acc[e]; best = e; } }
    float sc = 1.f / (1.f + expf(-bv));
    if (lane < E_NUM) out_scores[(size_t)lane * T_TOK + tok] = (lane == best) ? sc : 0.f;
    if (lane == 0) eidx[tok] = best;
    unsigned short* xbr = xb + (size_t)tok * H_DIM;
    unsigned short* xsr = xs + (size_t)tok * H_DIM;
#pragma unroll
    for (int i = 0; i < 8; i++) {
        int hb = i * 256 + lane * 4;
        ushort4 b, s4;
        b.x = f2bs(v[i].x); b.y = f2bs(v[i].y); b.z = f2bs(v[i].z); b.w = f2bs(v[i].w);
        s4.x = f2bs(v[i].x * sc); s4.y = f2bs(v[i].y * sc);
        s4.z = f2bs(v[i].z * sc); s4.w = f2bs(v[i].w * sc);
        *reinterpret_cast<ushort4*>(xbr + hb) = b;
        *reinterpret_cast<ushort4*>(xsr + hb) = s4;
    }
}

// ---------------- grouping ----------------
__global__ void group_kernel(const int* __restrict__ eidx, int* __restrict__ perm,
                             int* __restrict__ off) {
    __shared__ int cnt[E_NUM];
    __shared__ int base[E_NUM];
    int t = threadIdx.x;
    if (t < E_NUM) cnt[t] = 0;
    __syncthreads();
    for (int i = t; i < T_TOK; i += 256) atomicAdd(&cnt[eidx[i]], 1);
    __syncthreads();
    if (t == 0) {
        int s = 0;
        for (int e = 0; e < E_NUM; e++) { base[e] = s; off[e] = s; s += cnt[e]; }
        off[E_NUM] = s;
    }
    __syncthreads();
    for (int i = t; i < T_TOK; i += 256) {
        int e = eidx[i];
        int p = atomicAdd(&base[e], 1);
        perm[p] = i;
    }
}

// ---------------- GEMM1: q-depth-2 counted pipeline, BN=32 (32 gate + 32 up) ------
// 256 thr, BM=256, BK=64. As dbuf (GLL), B single-buf reg-staged, 2 q-sets.
// grid.x = I/32 (128), grid.y = g*8 + mt
__global__ __launch_bounds__(256, 2) void gemm1_kernel(
    const unsigned short* __restrict__ xb, const unsigned short* __restrict__ xs,
    const float* __restrict__ gup, const float* __restrict__ sg,
    const float* __restrict__ su, const int* __restrict__ perm,
    const int* __restrict__ off, unsigned short* __restrict__ hmid) {
    int nt = blockIdx.x;
    int g = blockIdx.y >> 3;
    int mt = blockIdx.y & 7;
    int rowbase, ng;
    if (g < E_NUM) { rowbase = off[g]; ng = off[g + 1] - rowbase; }
    else { rowbase = 0; ng = T_TOK; }
    int mstart = mt * BM;
    if (mstart >= ng) return;

    __shared__ unsigned short As[2][BM * BK];  // 2 x 32 KB
    __shared__ unsigned short Bg[BN * BK];     // 4 KB
    __shared__ unsigned short Bu[BN * BK];     // 4 KB

    int tid = threadIdx.x;
    int wave = tid >> 6, lane = tid & 63;
    int h = lane >> 4, ln = lane & 15;

    const unsigned short* Abase = (g == E_NUM) ? xb : xs;
    unsigned int aoff[8];
#pragma unroll
    for (int j = 0; j < 8; j++) {
        int r = wave * 64 + j * 8 + (lane >> 3);
        int sr = mstart + r; sr = (sr < ng) ? sr : (ng - 1);
        int tokr = (g < E_NUM) ? perm[rowbase + sr] : sr;
        aoff[j] = (unsigned int)tokr * H_DIM + A_SRC_CHUNK(lane);
    }
    int n0 = nt * BN;
    const float* gbase;
    const float* ubase;
    size_t ldb;
    if (g < E_NUM) {
        gbase = gup + (size_t)g * H_DIM * TWO_I + n0;
        ubase = gbase + I_DIM;
        ldb = TWO_I;
    } else {
        gbase = sg + n0;
        ubase = su + n0;
        ldb = I_DIM;
    }
    int kk = (tid >> 3) * 2;        // 2 k-rows per thread (covers 64)
    int nb = (tid & 7) * 4;         // 4 n-cols per thread (covers 32)
    const float* pg = gbase + (size_t)kk * ldb + nb;
    const float* pu = ubase + (size_t)kk * ldb + nb;

    f32x4 zero = {0.f, 0.f, 0.f, 0.f};
    f32x4 accg[4][2], accu[4][2];
#pragma unroll
    for (int i = 0; i < 4; i++)
#pragma unroll
        for (int j = 0; j < 2; j++) { accg[i][j] = zero; accu[i][j] = zero; }

    const int NT = H_DIM / BK;   // 32 (even)
    f32x4 Ag0, Ag1, Au0, Au1;    // q-set A
    f32x4 Bg0, Bg1, Bu0, Bu1;    // q-set B

#define G1_QLOAD(t_, QG0,QG1,QU0,QU1) { size_t ko_ = (size_t)(t_) * BK * ldb; \
        QG0 = *reinterpret_cast<const f32x4*>(pg + ko_); \
        QG1 = *reinterpret_cast<const f32x4*>(pg + ko_ + ldb); \
        QU0 = *reinterpret_cast<const f32x4*>(pu + ko_); \
        QU1 = *reinterpret_cast<const f32x4*>(pu + ko_ + ldb); }
#define G1_BWRITE(QG0,QG1,QU0,QU1) { _Pragma("unroll") \
        for (int i_ = 0; i_ < 4; i_++) { int n_ = nb + i_; \
            unsigned og_ = (unsigned)f2bs(QG0[i_]) | ((unsigned)f2bs(QG1[i_]) << 16); \
            unsigned ou_ = (unsigned)f2bs(QU0[i_]) | ((unsigned)f2bs(QU1[i_]) << 16); \
            int ob_ = (n_ * 128 + kk * 2) ^ BSWZ(n_); \
            *reinterpret_cast<unsigned*>((char*)Bg + ob_) = og_; \
            *reinterpret_cast<unsigned*>((char*)Bu + ob_) = ou_; } }
#define G1_AGLL(t_, buf_) { _Pragma("unroll") \
        for (int j_ = 0; j_ < 8; j_++) \
            GLL(Abase + aoff[j_] + (unsigned)(t_) * BK, \
                &As[buf_][(wave * 64 + j_ * 8) * BK]); }
#define G1_COMPUTE(buf_) { const unsigned short* Ab_ = &As[buf_][0]; \
        _Pragma("unroll") \
        for (int s_ = 0; s_ < 2; s_++) { \
            bf16x8 a0_ = aload(Ab_, wave * 64 + 0 * 16 + ln, s_, h); \
            bf16x8 a1_ = aload(Ab_, wave * 64 + 1 * 16 + ln, s_, h); \
            bf16x8 a2_ = aload(Ab_, wave * 64 + 2 * 16 + ln, s_, h); \
            bf16x8 a3_ = aload(Ab_, wave * 64 + 3 * 16 + ln, s_, h); \
            _Pragma("unroll") \
            for (int j_ = 0; j_ < 2; j_++) { \
                bf16x8 wg_ = bload(Bg, j_ * 16 + ln, s_, h); \
                accg[0][j_] = MFMA16(a0_, wg_, accg[0][j_]); \
                accg[1][j_] = MFMA16(a1_, wg_, accg[1][j_]); \
                accg[2][j_] = MFMA16(a2_, wg_, accg[2][j_]); \
                accg[3][j_] = MFMA16(a3_, wg_, accg[3][j_]); \
            } \
            _Pragma("unroll") \
            for (int j_ = 0; j_ < 2; j_++) { \
                bf16x8 wu_ = bload(Bu, j_ * 16 + ln, s_, h); \
                accu[0][j_] = MFMA16(a0_, wu_, accu[0][j_]); \
                accu[1][j_] = MFMA16(a1_, wu_, accu[1][j_]); \
                accu[2][j_] = MFMA16(a2_, wu_, accu[2][j_]); \
                accu[3][j_] = MFMA16(a3_, wu_, accu[3][j_]); \
            } \
        } }
// iter t: wait A(t) (16 newer VMEM ops), compute, refill (B t+1 / A t+2 / q t+3)
#define G1_SEG(t_, buf_, QG0,QG1,QU0,QU1) { \
        asm volatile("s_waitcnt vmcnt(16)" ::: "memory"); \
        G1_COMPUTE(buf_); \
        BARRIER(); \
        if ((t_) + 1 < NT) { \
            G1_BWRITE(QG0,QG1,QU0,QU1); \
            FENCE(); \
            { int tc_ = (t_) + 2; if (tc_ > NT - 1) tc_ = NT - 1; G1_AGLL(tc_, buf_); } \
            FENCE(); \
            { int tq_ = (t_) + 3; if (tq_ > NT - 1) tq_ = NT - 1; \
              G1_QLOAD(tq_, QG0,QG1,QU0,QU1); } \
            FENCE(); \
            BARRIER(); \
        } }

    // prologue: B(0)->LDS, A(0)->buf0, A(1)->buf1, B(1)->setB, B(2)->setA
    G1_QLOAD(0, Ag0,Ag1,Au0,Au1);
    FENCE();
    G1_AGLL(0, 0);
    FENCE();
    G1_AGLL(1, 1);
    FENCE();
    asm volatile("s_waitcnt vmcnt(16)" ::: "memory");  // B(0) q done (16 GLLs newer)
    G1_BWRITE(Ag0,Ag1,Au0,Au1);
    FENCE();
    G1_QLOAD(1, Bg0,Bg1,Bu0,Bu1);
    FENCE();
    G1_QLOAD(2, Ag0,Ag1,Au0,Au1);
    FENCE();
    BARRIER();

    for (int t = 0; t < NT; t += 2) {
        G1_SEG(t,     0, Bg0,Bg1,Bu0,Bu1)   // writes B(t+1) [odd -> set B]
        G1_SEG(t + 1, 1, Ag0,Ag1,Au0,Au1)   // writes B(t+2) [even -> set A]
    }

    int hbase = (g < E_NUM) ? rowbase : T_TOK;
#pragma unroll
    for (int i = 0; i < 4; i++) {
#pragma unroll
        for (int j = 0; j < 2; j++) {
#pragma unroll
            for (int r = 0; r < 4; r++) {
                int row = wave * 64 + i * 16 + h * 4 + r;
                int sr = mstart + row;
                if (sr < ng) {
                    float gv = accg[i][j][r], uv = accu[i][j][r];
                    float hv = gv / (1.f + expf(-gv)) * uv;  // silu(g)*u
                    int col = n0 + j * 16 + ln;
                    hmid[(size_t)(hbase + sr) * I_DIM + col] = f2bs(hv);
                }
            }
        }
    }
}

// ---------------- GEMM2: same pipeline, BN=32. ADD=0 shared writes, ADD=1 routed +=
// 256 thr, BM=256, BK=64. grid.x = H/32 (64). ADD=0: grid.y=mt(0..7); ADD=1: g*8+mt
template <int ADD>
__global__ __launch_bounds__(256, 2) void gemm2_kernel(
    const unsigned short* __restrict__ hmid, const float* __restrict__ dwn,
    const float* __restrict__ sd, const int* __restrict__ perm,
    const int* __restrict__ off, float* __restrict__ out) {
    int nt = blockIdx.x;
    int g, mt, rowbase, ng, hbase;
    if (ADD) {
        g = blockIdx.y >> 3; mt = blockIdx.y & 7;
        rowbase = off[g]; ng = off[g + 1] - rowbase; hbase = rowbase;
    } else {
        g = E_NUM; mt = blockIdx.y; rowbase = 0; ng = T_TOK; hbase = T_TOK;
    }
    int mstart = mt * BM;
    if (mstart >= ng) return;

    __shared__ unsigned short As[2][BM * BK];  // 2 x 32 KB
    __shared__ unsigned short Bs[BN * BK];     // 4 KB

    int tid = threadIdx.x;
    int wave = tid >> 6, lane = tid & 63;
    int h = lane >> 4, ln = lane & 15;

    unsigned int aoff[8];
#pragma unroll
    for (int j = 0; j < 8; j++) {
        int r = wave * 64 + j * 8 + (lane >> 3);
        int sr = mstart + r; sr = (sr < ng) ? sr : (ng - 1);
        aoff[j] = (unsigned int)(hbase + sr) * I_DIM + A_SRC_CHUNK(lane);
    }
    int n0 = nt * BN;
    const float* bbase = ADD ? (dwn + (size_t)g * I_DIM * H_DIM + n0) : (sd + n0);
    const size_t ldb = H_DIM;
    int kk = (tid >> 3) * 2;
    int nb = (tid & 7) * 4;
    const float* pb = bbase + (size_t)kk * ldb + nb;

    f32x4 zero = {0.f, 0.f, 0.f, 0.f};
    f32x4 acc[4][2];
#pragma unroll
    for (int i = 0; i < 4; i++)
#pragma unroll
        for (int j = 0; j < 2; j++) acc[i][j] = zero;

    const int NT2 = I_DIM / BK;  // 64 (even)
    f32x4 Qa0, Qa1, Qb0, Qb1;    // two q-sets

#define G2_QLOAD(t_, Q0,Q1) { size_t ko_ = (size_t)(t_) * BK * ldb; \
        Q0 = *reinterpret_cast<const f32x4*>(pb + ko_); \
        Q1 = *reinterpret_cast<const f32x4*>(pb + ko_ + ldb); }
#define G2_BWRITE(Q0,Q1) { _Pragma("unroll") \
        for (int i_ = 0; i_ < 4; i_++) { int n_ = nb + i_; \
            unsigned o_ = (unsigned)f2bs(Q0[i_]) | ((unsigned)f2bs(Q1[i_]) << 16); \
            int ob_ = (n_ * 128 + kk * 2) ^ BSWZ(n_); \
            *reinterpret_cast<unsigned*>((char*)Bs + ob_) = o_; } }
#define G2_AGLL(t_, buf_) { _Pragma("unroll") \
        for (int j_ = 0; j_ < 8; j_++) \
            GLL(hmid + aoff[j_] + (unsigned)(t_) * BK, \
                &As[buf_][(wave * 64 + j_ * 8) * BK]); }
#define G2_COMPUTE(buf_) { const unsigned short* Ab_ = &As[buf_][0]; \
        _Pragma("unroll") \
        for (int s_ = 0; s_ < 2; s_++) { \
            bf16x8 a0_ = aload(Ab_, wave * 64 + 0 * 16 + ln, s_, h); \
            bf16x8 a1_ = aload(Ab_, wave * 64 + 1 * 16 + ln, s_, h); \
            bf16x8 a2_ = aload(Ab_, wave * 64 + 2 * 16 + ln, s_, h); \
            bf16x8 a3_ = aload(Ab_, wave * 64 + 3 * 16 + ln, s_, h); \
            _Pragma("unroll") \
            for (int j_ = 0; j_ < 2; j_++) { \
                bf16x8 wb_ = bload(Bs, j_ * 16 + ln, s_, h); \
                acc[0][j_] = MFMA16(a0_, wb_, acc[0][j_]); \
                acc[1][j_] = MFMA16(a1_, wb_, acc[1][j_]); \
                acc[2][j_] = MFMA16(a2_, wb_, acc[2][j_]); \
                acc[3][j_] = MFMA16(a3_, wb_, acc[3][j_]); \
            } \
        } }
#define G2_SEG(t_, buf_, Q0,Q1) { \
        asm volatile("s_waitcnt vmcnt(12)" ::: "memory"); \
        G2_COMPUTE(buf_); \
        BARRIER(); \
        if ((t_) + 1 < NT2) { \
            G2_BWRITE(Q0,Q1); \
            FENCE(); \
            { int tc_ = (t_) + 2; if (tc_ > NT2 - 1) tc_ = NT2 - 1; G2_AGLL(tc_, buf_); } \
            FENCE(); \
            { int tq_ = (t_) + 3; if (tq_ > NT2 - 1) tq_ = NT2 - 1; \
              G2_QLOAD(tq_, Q0,Q1); } \
            FENCE(); \
            BARRIER(); \
        } }

    G2_QLOAD(0, Qa0,Qa1);
    FENCE();
    G2_AGLL(0, 0);
    FENCE();
    G2_AGLL(1, 1);
    FENCE();
    asm volatile("s_waitcnt vmcnt(16)" ::: "memory");  // B(0) q done (16 GLLs newer)
    G2_BWRITE(Qa0,Qa1);
    FENCE();
    G2_QLOAD(1, Qb0,Qb1);
    FENCE();
    G2_QLOAD(2, Qa0,Qa1);
    FENCE();
    BARRIER();

    for (int t = 0; t < NT2; t += 2) {
        G2_SEG(t,     0, Qb0,Qb1)
        G2_SEG(t + 1, 1, Qa0,Qa1)
    }

#pragma unroll
    for (int i = 0; i < 4; i++) {
#pragma unroll
        for (int j = 0; j < 2; j++) {
#pragma unroll
            for (int r = 0; r < 4; r++) {
                int row = wave * 64 + i * 16 + h * 4 + r;
                int sr = mstart + row;
                if (sr < ng) {
                    int tok = ADD ? perm[rowbase + sr] : sr;
                    int col = n0 + j * 16 + ln;
                    float v = acc[i][j][r];
                    float* o = out + (size_t)tok * H_DIM + col;
                    if (ADD) *o += v; else *o = v;
                }
            }
        }
    }
}

extern "C" void kernel_launch(void* const* d_in, const int* in_sizes, int n_in,
                              void* d_out, int out_size, void* d_ws, size_t ws_size,
                              hipStream_t stream) {
    (void)in_sizes; (void)n_in; (void)out_size;
    const float* hs  = (const float*)d_in[0];
    const float* rw  = (const float*)d_in[1];
    const float* gup = (const float*)d_in[2];
    const float* dwn = (const float*)d_in[3];
    const float* sg  = (const float*)d_in[4];
    const float* su  = (const float*)d_in[5];
    const float* sd  = (const float*)d_in[6];
    float* out = (float*)d_out;
    float* out_scores = out + (size_t)T_TOK * H_DIM;

    char* w = (char*)d_ws;
    size_t o = 0;
    auto alloc = [&](size_t bytes) {
        void* p = w + o;
        o += (bytes + 255) & ~(size_t)255;
        return p;
    };
    unsigned short* xb   = (unsigned short*)alloc((size_t)T_TOK * H_DIM * 2);
    unsigned short* xs   = (unsigned short*)alloc((size_t)T_TOK * H_DIM * 2);
    unsigned short* hmid = (unsigned short*)alloc((size_t)2 * T_TOK * I_DIM * 2);
    int* eidx    = (int*)alloc(T_TOK * 4);
    int* perm    = (int*)alloc(T_TOK * 4);
    int* off     = (int*)alloc(64 * 4);
    if (ws_size < o) return;  // insufficient workspace

    router_convert_kernel<<<T_TOK / 4, 256, 0, stream>>>(hs, rw, out_scores, eidx, xb, xs);
    group_kernel<<<1, 256, 0, stream>>>(eidx, perm, off);

    gemm1_kernel<<<dim3(I_DIM / BN, 9 * 8), 256, 0, stream>>>(
        xb, xs, gup, sg, su, perm, off, hmid);
    gemm2_kernel<0><<<dim3(H_DIM / BN, 8), 256, 0, stream>>>(hmid, dwn, sd, perm, off, out);
    gemm2_kernel<1><<<dim3(H_DIM / BN, E_NUM * 8), 256, 0, stream>>>(hmid, dwn, sd, perm, off, out);
}

// Round 14
// 530.718 us; speedup vs baseline: 1.8799x; 1.1564x over previous
//
#include <hip/hip_runtime.h>
#include <hip/hip_bf16.h>

#define H_DIM 2048
#define E_NUM 8
#define I_DIM 4096
#define TWO_I 8192
#define T_TOK 2048

#define BM 256
#define BN 64
#define BK 64

typedef __bf16 bf16x8 __attribute__((ext_vector_type(8)));
typedef float f32x4 __attribute__((ext_vector_type(4)));

static __device__ __forceinline__ unsigned short f2bs(float x) {
    __hip_bfloat16 h = __float2bfloat16(x);
    return __builtin_bit_cast(unsigned short, h);
}

#define GLL(gsrc, ldst) __builtin_amdgcn_global_load_lds( \
    (const __attribute__((address_space(1))) void*)(gsrc), \
    (__attribute__((address_space(3))) void*)(ldst), 16, 0, 0)

#define MFMA16(a, b, c) __builtin_amdgcn_mfma_f32_16x16x32_bf16(a, b, c, 0, 0, 0)
#define BSWZ(n) (((((n) & 7) ^ (((n) >> 2) & 7))) << 4)
#define A_SRC_CHUNK(lane) ((((lane) & 7) ^ (((lane) >> 3) & 7)) * 8)
// barrier WITHOUT vmcnt drain: LDS writes visible; global/GLL loads stay in flight
#define BARRIER() asm volatile("s_waitcnt lgkmcnt(0)\ns_barrier" ::: "memory")
// compiler-order fence (free at runtime): pins VMEM issue order so counted waits stay exact
#define FENCE() asm volatile("" ::: "memory")

static __device__ __forceinline__ bf16x8 bload(
    const unsigned short* __restrict__ Bs, int n, int s, int h) {
    int off = (n * 128 + s * 64 + h * 16) ^ BSWZ(n);
    return *reinterpret_cast<const bf16x8*>((const char*)Bs + off);
}

static __device__ __forceinline__ bf16x8 aload(
    const unsigned short* __restrict__ As, int row, int s, int h) {
    int off = row * 128 + ((s * 64 + h * 16) ^ ((row & 7) << 4));
    return *reinterpret_cast<const bf16x8*>((const char*)As + off);
}

// ---------------- fused router + convert: one wave per token ----------------
__global__ __launch_bounds__(256) void router_convert_kernel(
    const float* __restrict__ hs, const float* __restrict__ rw,
    float* __restrict__ out_scores, int* __restrict__ eidx,
    unsigned short* __restrict__ xb, unsigned short* __restrict__ xs) {
    int tok = blockIdx.x * 4 + (threadIdx.x >> 6);
    int lane = threadIdx.x & 63;
    const float* row = hs + (size_t)tok * H_DIM;
    float4 v[8];
    float acc[E_NUM];
#pragma unroll
    for (int e = 0; e < E_NUM; e++) acc[e] = 0.f;
#pragma unroll
    for (int i = 0; i < 8; i++) {
        int hb = i * 256 + lane * 4;
        v[i] = *reinterpret_cast<const float4*>(row + hb);
        const float* w0 = rw + (size_t)hb * E_NUM;
#pragma unroll
        for (int e = 0; e < E_NUM; e++) {
            acc[e] += v[i].x * w0[e] + v[i].y * w0[E_NUM + e] +
                      v[i].z * w0[2 * E_NUM + e] + v[i].w * w0[3 * E_NUM + e];
        }
    }
#pragma unroll
    for (int e = 0; e < E_NUM; e++) {
#pragma unroll
        for (int o = 32; o > 0; o >>= 1) acc[e] += __shfl_xor(acc[e], o, 64);
    }
    int best = 0; float bv = acc[0];
#pragma unroll
    for (int e = 1; e < E_NUM; e++) { if (acc[e] > bv) { bv = acc[e]; best = e; } }
    float sc = 1.f / (1.f + expf(-bv));
    if (lane < E_NUM) out_scores[(size_t)lane * T_TOK + tok] = (lane == best) ? sc : 0.f;
    if (lane == 0) eidx[tok] = best;
    unsigned short* xbr = xb + (size_t)tok * H_DIM;
    unsigned short* xsr = xs + (size_t)tok * H_DIM;
#pragma unroll
    for (int i = 0; i < 8; i++) {
        int hb = i * 256 + lane * 4;
        ushort4 b, s4;
        b.x = f2bs(v[i].x); b.y = f2bs(v[i].y); b.z = f2bs(v[i].z); b.w = f2bs(v[i].w);
        s4.x = f2bs(v[i].x * sc); s4.y = f2bs(v[i].y * sc);
        s4.z = f2bs(v[i].z * sc); s4.w = f2bs(v[i].w * sc);
        *reinterpret_cast<ushort4*>(xbr + hb) = b;
        *reinterpret_cast<ushort4*>(xsr + hb) = s4;
    }
}

// ---------------- grouping ----------------
__global__ void group_kernel(const int* __restrict__ eidx, int* __restrict__ perm,
                             int* __restrict__ off) {
    __shared__ int cnt[E_NUM];
    __shared__ int base[E_NUM];
    int t = threadIdx.x;
    if (t < E_NUM) cnt[t] = 0;
    __syncthreads();
    for (int i = t; i < T_TOK; i += 256) atomicAdd(&cnt[eidx[i]], 1);
    __syncthreads();
    if (t == 0) {
        int s = 0;
        for (int e = 0; e < E_NUM; e++) { base[e] = s; off[e] = s; s += cnt[e]; }
        off[E_NUM] = s;
    }
    __syncthreads();
    for (int i = t; i < T_TOK; i += 256) {
        int e = eidx[i];
        int p = atomicAdd(&base[e], 1);
        perm[p] = i;
    }
}

// ---------------- GEMM1: R9 structure, swapped refill order + counted pre-compute wait
// 256 thr, BM=256, BN=64 gate + 64 up, BK=64. As dbuf (GLL), B single-buf reg-staged.
// Steady invariant at compute(t): outstanding = A(t)[8] Q(t+1)[8] A(t+1)[8]; vmcnt(16)
// drains exactly A(t). BWRITE's implicit wait = vmcnt(8) (A(t+1) stays in flight).
// grid.x = I/64, grid.y = g*8 + mt
__global__ __launch_bounds__(256, 2) void gemm1_kernel(
    const unsigned short* __restrict__ xb, const unsigned short* __restrict__ xs,
    const float* __restrict__ gup, const float* __restrict__ sg,
    const float* __restrict__ su, const int* __restrict__ perm,
    const int* __restrict__ off, unsigned short* __restrict__ hmid) {
    int nt = blockIdx.x;
    int g = blockIdx.y >> 3;
    int mt = blockIdx.y & 7;
    int rowbase, ng;
    if (g < E_NUM) { rowbase = off[g]; ng = off[g + 1] - rowbase; }
    else { rowbase = 0; ng = T_TOK; }
    int mstart = mt * BM;
    if (mstart >= ng) return;

    __shared__ unsigned short As[2][BM * BK];  // 2 x 32 KB
    __shared__ unsigned short Bg[BN * BK];     // 8 KB
    __shared__ unsigned short Bu[BN * BK];     // 8 KB

    int tid = threadIdx.x;
    int wave = tid >> 6, lane = tid & 63;
    int h = lane >> 4, ln = lane & 15;

    const unsigned short* Abase = (g == E_NUM) ? xb : xs;
    unsigned int aoff[8];
#pragma unroll
    for (int j = 0; j < 8; j++) {
        int r = wave * 64 + j * 8 + (lane >> 3);
        int sr = mstart + r; sr = (sr < ng) ? sr : (ng - 1);
        int tokr = (g < E_NUM) ? perm[rowbase + sr] : sr;
        aoff[j] = (unsigned int)tokr * H_DIM + A_SRC_CHUNK(lane);
    }
    int n0 = nt * BN;
    const float* gbase;
    const float* ubase;
    size_t ldb;
    if (g < E_NUM) {
        gbase = gup + (size_t)g * H_DIM * TWO_I + n0;
        ubase = gbase + I_DIM;
        ldb = TWO_I;
    } else {
        gbase = sg + n0;
        ubase = su + n0;
        ldb = I_DIM;
    }
    int k0i = wave * 16 + ((lane >> 4) << 2);  // 4 k-rows per lane
    int nb = (lane & 15) << 2;                 // 4 n-cols per lane
    const float* pg = gbase + (size_t)k0i * ldb + nb;
    const float* pu = ubase + (size_t)k0i * ldb + nb;

    f32x4 zero = {0.f, 0.f, 0.f, 0.f};
    f32x4 accg[4][4], accu[4][4];
#pragma unroll
    for (int i = 0; i < 4; i++)
#pragma unroll
        for (int j = 0; j < 4; j++) { accg[i][j] = zero; accu[i][j] = zero; }

    const int NT = H_DIM / BK;   // 32
    f32x4 qg0, qg1, qg2, qg3, qu0, qu1, qu2, qu3;

#define G1_QLOAD(t_) { size_t ko_ = (size_t)(t_) * BK * ldb; \
        const float* p_ = pg + ko_; \
        qg0 = *reinterpret_cast<const f32x4*>(p_); \
        qg1 = *reinterpret_cast<const f32x4*>(p_ + ldb); \
        qg2 = *reinterpret_cast<const f32x4*>(p_ + 2 * ldb); \
        qg3 = *reinterpret_cast<const f32x4*>(p_ + 3 * ldb); \
        p_ = pu + ko_; \
        qu0 = *reinterpret_cast<const f32x4*>(p_); \
        qu1 = *reinterpret_cast<const f32x4*>(p_ + ldb); \
        qu2 = *reinterpret_cast<const f32x4*>(p_ + 2 * ldb); \
        qu3 = *reinterpret_cast<const f32x4*>(p_ + 3 * ldb); }
#define G1_BWRITE() { _Pragma("unroll") \
        for (int i_ = 0; i_ < 4; i_++) { int n_ = nb + i_; \
            ushort4 og_, ou_; \
            og_.x = f2bs(qg0[i_]); og_.y = f2bs(qg1[i_]); \
            og_.z = f2bs(qg2[i_]); og_.w = f2bs(qg3[i_]); \
            ou_.x = f2bs(qu0[i_]); ou_.y = f2bs(qu1[i_]); \
            ou_.z = f2bs(qu2[i_]); ou_.w = f2bs(qu3[i_]); \
            int ob_ = (n_ * 128 + k0i * 2) ^ BSWZ(n_); \
            *reinterpret_cast<ushort4*>((char*)Bg + ob_) = og_; \
            *reinterpret_cast<ushort4*>((char*)Bu + ob_) = ou_; } }
#define G1_AGLL(t_, buf_) { _Pragma("unroll") \
        for (int j_ = 0; j_ < 8; j_++) \
            GLL(Abase + aoff[j_] + (unsigned)(t_) * BK, \
                &As[buf_][(wave * 64 + j_ * 8) * BK]); }

    // prologue: B(0)->LDS, A(0)->buf0, B(1)->regs, A(1)->buf1
    G1_QLOAD(0);
    asm volatile("s_waitcnt vmcnt(0)" ::: "memory");
    G1_BWRITE();
    FENCE();
    G1_AGLL(0, 0);
    FENCE();
    G1_QLOAD(1);
    FENCE();
    G1_AGLL(1, 1);
    BARRIER();

    for (int t = 0; t < NT; ++t) {
        asm volatile("s_waitcnt vmcnt(16)" ::: "memory");  // A(t) landed; Q(t+1),A(t+1) in flight
        const unsigned short* Ab = &As[t & 1][0];
#pragma unroll
        for (int s = 0; s < 2; s++) {
            bf16x8 a0 = aload(Ab, wave * 64 + 0 * 16 + ln, s, h);
            bf16x8 a1 = aload(Ab, wave * 64 + 1 * 16 + ln, s, h);
            bf16x8 a2 = aload(Ab, wave * 64 + 2 * 16 + ln, s, h);
            bf16x8 a3 = aload(Ab, wave * 64 + 3 * 16 + ln, s, h);
#pragma unroll
            for (int j = 0; j < 4; j++) {
                bf16x8 bg = bload(Bg, j * 16 + ln, s, h);
                accg[0][j] = MFMA16(a0, bg, accg[0][j]);
                accg[1][j] = MFMA16(a1, bg, accg[1][j]);
                accg[2][j] = MFMA16(a2, bg, accg[2][j]);
                accg[3][j] = MFMA16(a3, bg, accg[3][j]);
            }
#pragma unroll
            for (int j = 0; j < 4; j++) {
                bf16x8 bu = bload(Bu, j * 16 + ln, s, h);
                accu[0][j] = MFMA16(a0, bu, accu[0][j]);
                accu[1][j] = MFMA16(a1, bu, accu[1][j]);
                accu[2][j] = MFMA16(a2, bu, accu[2][j]);
                accu[3][j] = MFMA16(a3, bu, accu[3][j]);
            }
        }
        BARRIER();                       // reads of As[t&1], B(t) done
        if (t + 1 < NT) {
            G1_BWRITE();                 // B(t+1); implicit counted wait ~vmcnt(8)
            FENCE();
            int tc = t + 2; if (tc > NT - 1) tc = NT - 1;
            G1_QLOAD(tc);                // B(t+2) -> freed q-regs, stays in flight
            FENCE();
            G1_AGLL(tc, t & 1);          // A(t+2): issued LAST, 2 iters of cover
            BARRIER();                   // B(t+1) visible; loads NOT drained
        }
    }

    int hbase = (g < E_NUM) ? rowbase : T_TOK;
#pragma unroll
    for (int i = 0; i < 4; i++) {
#pragma unroll
        for (int j = 0; j < 4; j++) {
#pragma unroll
            for (int r = 0; r < 4; r++) {
                int row = wave * 64 + i * 16 + h * 4 + r;
                int sr = mstart + row;
                if (sr < ng) {
                    float gv = accg[i][j][r], uv = accu[i][j][r];
                    float hv = gv / (1.f + expf(-gv)) * uv;  // silu(g)*u
                    int col = n0 + j * 16 + ln;
                    hmid[(size_t)(hbase + sr) * I_DIM + col] = f2bs(hv);
                }
            }
        }
    }
}

// ---------------- GEMM2: same swapped schedule. ADD=0 shared writes, ADD=1 routed +=
// 256 thr, BM=256, BN=64, BK=64. grid.x = H/64. ADD=0: grid.y=mt(0..7); ADD=1: g*8+mt
template <int ADD>
__global__ __launch_bounds__(256, 2) void gemm2_kernel(
    const unsigned short* __restrict__ hmid, const float* __restrict__ dwn,
    const float* __restrict__ sd, const int* __restrict__ perm,
    const int* __restrict__ off, float* __restrict__ out) {
    int nt = blockIdx.x;
    int g, mt, rowbase, ng, hbase;
    if (ADD) {
        g = blockIdx.y >> 3; mt = blockIdx.y & 7;
        rowbase = off[g]; ng = off[g + 1] - rowbase; hbase = rowbase;
    } else {
        g = E_NUM; mt = blockIdx.y; rowbase = 0; ng = T_TOK; hbase = T_TOK;
    }
    int mstart = mt * BM;
    if (mstart >= ng) return;

    __shared__ unsigned short As[2][BM * BK];  // 2 x 32 KB
    __shared__ unsigned short Bs[BN * BK];     // 8 KB

    int tid = threadIdx.x;
    int wave = tid >> 6, lane = tid & 63;
    int h = lane >> 4, ln = lane & 15;

    unsigned int aoff[8];
#pragma unroll
    for (int j = 0; j < 8; j++) {
        int r = wave * 64 + j * 8 + (lane >> 3);
        int sr = mstart + r; sr = (sr < ng) ? sr : (ng - 1);
        aoff[j] = (unsigned int)(hbase + sr) * I_DIM + A_SRC_CHUNK(lane);
    }
    int n0 = nt * BN;
    const float* bbase = ADD ? (dwn + (size_t)g * I_DIM * H_DIM + n0) : (sd + n0);
    const size_t ldb = H_DIM;
    int k0i = wave * 16 + ((lane >> 4) << 2);
    int nb = (lane & 15) << 2;
    const float* pb = bbase + (size_t)k0i * ldb + nb;

    f32x4 zero = {0.f, 0.f, 0.f, 0.f};
    f32x4 acc[4][4];
#pragma unroll
    for (int i = 0; i < 4; i++)
#pragma unroll
        for (int j = 0; j < 4; j++) acc[i][j] = zero;

    const int NT2 = I_DIM / BK;  // 64
    f32x4 qb0, qb1, qb2, qb3;

#define G2_QLOAD(t_) { size_t ko_ = (size_t)(t_) * BK * ldb; \
        const float* p_ = pb + ko_; \
        qb0 = *reinterpret_cast<const f32x4*>(p_); \
        qb1 = *reinterpret_cast<const f32x4*>(p_ + ldb); \
        qb2 = *reinterpret_cast<const f32x4*>(p_ + 2 * ldb); \
        qb3 = *reinterpret_cast<const f32x4*>(p_ + 3 * ldb); }
#define G2_BWRITE() { _Pragma("unroll") \
        for (int i_ = 0; i_ < 4; i_++) { int n_ = nb + i_; \
            ushort4 o_; \
            o_.x = f2bs(qb0[i_]); o_.y = f2bs(qb1[i_]); \
            o_.z = f2bs(qb2[i_]); o_.w = f2bs(qb3[i_]); \
            int ob_ = (n_ * 128 + k0i * 2) ^ BSWZ(n_); \
            *reinterpret_cast<ushort4*>((char*)Bs + ob_) = o_; } }
#define G2_AGLL(t_, buf_) { _Pragma("unroll") \
        for (int j_ = 0; j_ < 8; j_++) \
            GLL(hmid + aoff[j_] + (unsigned)(t_) * BK, \
                &As[buf_][(wave * 64 + j_ * 8) * BK]); }

    G2_QLOAD(0);
    asm volatile("s_waitcnt vmcnt(0)" ::: "memory");
    G2_BWRITE();
    FENCE();
    G2_AGLL(0, 0);
    FENCE();
    G2_QLOAD(1);
    FENCE();
    G2_AGLL(1, 1);
    BARRIER();

    for (int t = 0; t < NT2; ++t) {
        asm volatile("s_waitcnt vmcnt(12)" ::: "memory");  // A(t) landed; Q(t+1),A(t+1) in flight
        const unsigned short* Ab = &As[t & 1][0];
#pragma unroll
        for (int s = 0; s < 2; s++) {
            bf16x8 a0 = aload(Ab, wave * 64 + 0 * 16 + ln, s, h);
            bf16x8 a1 = aload(Ab, wave * 64 + 1 * 16 + ln, s, h);
            bf16x8 a2 = aload(Ab, wave * 64 + 2 * 16 + ln, s, h);
            bf16x8 a3 = aload(Ab, wave * 64 + 3 * 16 + ln, s, h);
#pragma unroll
            for (int j = 0; j < 4; j++) {
                bf16x8 b = bload(Bs, j * 16 + ln, s, h);
                acc[0][j] = MFMA16(a0, b, acc[0][j]);
                acc[1][j] = MFMA16(a1, b, acc[1][j]);
                acc[2][j] = MFMA16(a2, b, acc[2][j]);
                acc[3][j] = MFMA16(a3, b, acc[3][j]);
            }
        }
        BARRIER();
        if (t + 1 < NT2) {
            G2_BWRITE();
            FENCE();
            int tc = t + 2; if (tc > NT2 - 1) tc = NT2 - 1;
            G2_QLOAD(tc);
            FENCE();
            G2_AGLL(tc, t & 1);
            BARRIER();
        }
    }

#pragma unroll
    for (int i = 0; i < 4; i++) {
#pragma unroll
        for (int j = 0; j < 4; j++) {
#pragma unroll
            for (int r = 0; r < 4; r++) {
                int row = wave * 64 + i * 16 + h * 4 + r;
                int sr = mstart + row;
                if (sr < ng) {
                    int tok = ADD ? perm[rowbase + sr] : sr;
                    int col = n0 + j * 16 + ln;
                    float v = acc[i][j][r];
                    float* o = out + (size_t)tok * H_DIM + col;
                    if (ADD) *o += v; else *o = v;
                }
            }
        }
    }
}

extern "C" void kernel_launch(void* const* d_in, const int* in_sizes, int n_in,
                              void* d_out, int out_size, void* d_ws, size_t ws_size,
                              hipStream_t stream) {
    (void)in_sizes; (void)n_in; (void)out_size;
    const float* hs  = (const float*)d_in[0];
    const float* rw  = (const float*)d_in[1];
    const float* gup = (const float*)d_in[2];
    const float* dwn = (const float*)d_in[3];
    const float* sg  = (const float*)d_in[4];
    const float* su  = (const float*)d_in[5];
    const float* sd  = (const float*)d_in[6];
    float* out = (float*)d_out;
    float* out_scores = out + (size_t)T_TOK * H_DIM;

    char* w = (char*)d_ws;
    size_t o = 0;
    auto alloc = [&](size_t bytes) {
        void* p = w + o;
        o += (bytes + 255) & ~(size_t)255;
        return p;
    };
    unsigned short* xb   = (unsigned short*)alloc((size_t)T_TOK * H_DIM * 2);
    unsigned short* xs   = (unsigned short*)alloc((size_t)T_TOK * H_DIM * 2);
    unsigned short* hmid = (unsigned short*)alloc((size_t)2 * T_TOK * I_DIM * 2);
    int* eidx    = (int*)alloc(T_TOK * 4);
    int* perm    = (int*)alloc(T_TOK * 4);
    int* off     = (int*)alloc(64 * 4);
    if (ws_size < o) return;  // insufficient workspace

    router_convert_kernel<<<T_TOK / 4, 256, 0, stream>>>(hs, rw, out_scores, eidx, xb, xs);
    group_kernel<<<1, 256, 0, stream>>>(eidx, perm, off);

    gemm1_kernel<<<dim3(I_DIM / BN, 9 * 8), 256, 0, stream>>>(
        xb, xs, gup, sg, su, perm, off, hmid);
    gemm2_kernel<0><<<dim3(H_DIM / BN, 8), 256, 0, stream>>>(hmid, dwn, sd, perm, off, out);
    gemm2_kernel<1><<<dim3(H_DIM / BN, E_NUM * 8), 256, 0, stream>>>(hmid, dwn, sd, perm, off, out);
}

// Round 15
// 488.740 us; speedup vs baseline: 2.0414x; 1.0859x over previous
//
#include <hip/hip_runtime.h>
#include <hip/hip_bf16.h>

#define H_DIM 2048
#define E_NUM 8
#define I_DIM 4096
#define TWO_I 8192
#define T_TOK 2048

#define BM 256
#define BN 64
#define BK 64

typedef __bf16 bf16x8 __attribute__((ext_vector_type(8)));
typedef float f32x4 __attribute__((ext_vector_type(4)));

static __device__ __forceinline__ unsigned short f2bs(float x) {
    __hip_bfloat16 h = __float2bfloat16(x);
    return __builtin_bit_cast(unsigned short, h);
}

#define GLL(gsrc, ldst) __builtin_amdgcn_global_load_lds( \
    (const __attribute__((address_space(1))) void*)(gsrc), \
    (__attribute__((address_space(3))) void*)(ldst), 16, 0, 0)

#define MFMA16(a, b, c) __builtin_amdgcn_mfma_f32_16x16x32_bf16(a, b, c, 0, 0, 0)
#define BSWZ(n) (((((n) & 7) ^ (((n) >> 2) & 7))) << 4)
#define A_SRC_CHUNK(lane) ((((lane) & 7) ^ (((lane) >> 3) & 7)) * 8)
// barrier WITHOUT vmcnt drain: LDS writes visible; global/GLL loads stay in flight
#define BARRIER() asm volatile("s_waitcnt lgkmcnt(0)\ns_barrier" ::: "memory")

static __device__ __forceinline__ bf16x8 bload(
    const unsigned short* __restrict__ Bs, int n, int s, int h) {
    int off = (n * 128 + s * 64 + h * 16) ^ BSWZ(n);
    return *reinterpret_cast<const bf16x8*>((const char*)Bs + off);
}

static __device__ __forceinline__ bf16x8 aload(
    const unsigned short* __restrict__ As, int row, int s, int h) {
    int off = row * 128 + ((s * 64 + h * 16) ^ ((row & 7) << 4));
    return *reinterpret_cast<const bf16x8*>((const char*)As + off);
}

// ---------------- fused router + convert: one wave per token ----------------
__global__ __launch_bounds__(256) void router_convert_kernel(
    const float* __restrict__ hs, const float* __restrict__ rw,
    float* __restrict__ out_scores, int* __restrict__ eidx,
    unsigned short* __restrict__ xb, unsigned short* __restrict__ xs) {
    int tok = blockIdx.x * 4 + (threadIdx.x >> 6);
    int lane = threadIdx.x & 63;
    const float* row = hs + (size_t)tok * H_DIM;
    float4 v[8];
    float acc[E_NUM];
#pragma unroll
    for (int e = 0; e < E_NUM; e++) acc[e] = 0.f;
#pragma unroll
    for (int i = 0; i < 8; i++) {
        int hb = i * 256 + lane * 4;
        v[i] = *reinterpret_cast<const float4*>(row + hb);
        const float* w0 = rw + (size_t)hb * E_NUM;
#pragma unroll
        for (int e = 0; e < E_NUM; e++) {
            acc[e] += v[i].x * w0[e] + v[i].y * w0[E_NUM + e] +
                      v[i].z * w0[2 * E_NUM + e] + v[i].w * w0[3 * E_NUM + e];
        }
    }
#pragma unroll
    for (int e = 0; e < E_NUM; e++) {
#pragma unroll
        for (int o = 32; o > 0; o >>= 1) acc[e] += __shfl_xor(acc[e], o, 64);
    }
    int best = 0; float bv = acc[0];
#pragma unroll
    for (int e = 1; e < E_NUM; e++) { if (acc[e] > bv) { bv = acc[e]; best = e; } }
    float sc = 1.f / (1.f + expf(-bv));
    if (lane < E_NUM) out_scores[(size_t)lane * T_TOK + tok] = (lane == best) ? sc : 0.f;
    if (lane == 0) eidx[tok] = best;
    unsigned short* xbr = xb + (size_t)tok * H_DIM;
    unsigned short* xsr = xs + (size_t)tok * H_DIM;
#pragma unroll
    for (int i = 0; i < 8; i++) {
        int hb = i * 256 + lane * 4;
        ushort4 b, s4;
        b.x = f2bs(v[i].x); b.y = f2bs(v[i].y); b.z = f2bs(v[i].z); b.w = f2bs(v[i].w);
        s4.x = f2bs(v[i].x * sc); s4.y = f2bs(v[i].y * sc);
        s4.z = f2bs(v[i].z * sc); s4.w = f2bs(v[i].w * sc);
        *reinterpret_cast<ushort4*>(xbr + hb) = b;
        *reinterpret_cast<ushort4*>(xsr + hb) = s4;
    }
}

// ---------------- grouping ----------------
__global__ void group_kernel(const int* __restrict__ eidx, int* __restrict__ perm,
                             int* __restrict__ off) {
    __shared__ int cnt[E_NUM];
    __shared__ int base[E_NUM];
    int t = threadIdx.x;
    if (t < E_NUM) cnt[t] = 0;
    __syncthreads();
    for (int i = t; i < T_TOK; i += 256) atomicAdd(&cnt[eidx[i]], 1);
    __syncthreads();
    if (t == 0) {
        int s = 0;
        for (int e = 0; e < E_NUM; e++) { base[e] = s; off[e] = s; s += cnt[e]; }
        off[E_NUM] = s;
    }
    __syncthreads();
    for (int i = t; i < T_TOK; i += 256) {
        int e = eidx[i];
        int p = atomicAdd(&base[e], 1);
        perm[p] = i;
    }
}

// ---------------- GEMM1: R9 schedule, 512 thr (8 waves x 32 rows), 16 waves/CU ------
// BM=256, BN=64 gate + 64 up, BK=64. As dbuf (GLL), B single-buf reg-staged. 80 KB LDS.
// grid.x = I/64, grid.y = g*8 + mt
__global__ __launch_bounds__(512, 4) void gemm1_kernel(
    const unsigned short* __restrict__ xb, const unsigned short* __restrict__ xs,
    const float* __restrict__ gup, const float* __restrict__ sg,
    const float* __restrict__ su, const int* __restrict__ perm,
    const int* __restrict__ off, unsigned short* __restrict__ hmid) {
    int nt = blockIdx.x;
    int g = blockIdx.y >> 3;
    int mt = blockIdx.y & 7;
    int rowbase, ng;
    if (g < E_NUM) { rowbase = off[g]; ng = off[g + 1] - rowbase; }
    else { rowbase = 0; ng = T_TOK; }
    int mstart = mt * BM;
    if (mstart >= ng) return;

    __shared__ unsigned short As[2][BM * BK];  // 2 x 32 KB
    __shared__ unsigned short Bg[BN * BK];     // 8 KB
    __shared__ unsigned short Bu[BN * BK];     // 8 KB

    int tid = threadIdx.x;
    int wave = tid >> 6, lane = tid & 63;
    int h = lane >> 4, ln = lane & 15;

    const unsigned short* Abase = (g == E_NUM) ? xb : xs;
    unsigned int aoff[4];
#pragma unroll
    for (int j = 0; j < 4; j++) {
        int r = wave * 32 + j * 8 + (lane >> 3);
        int sr = mstart + r; sr = (sr < ng) ? sr : (ng - 1);
        int tokr = (g < E_NUM) ? perm[rowbase + sr] : sr;
        aoff[j] = (unsigned int)tokr * H_DIM + A_SRC_CHUNK(lane);
    }
    int n0 = nt * BN;
    const float* gbase;
    const float* ubase;
    size_t ldb;
    if (g < E_NUM) {
        gbase = gup + (size_t)g * H_DIM * TWO_I + n0;
        ubase = gbase + I_DIM;
        ldb = TWO_I;
    } else {
        gbase = sg + n0;
        ubase = su + n0;
        ldb = I_DIM;
    }
    int k0i = (tid >> 4) * 2;       // 2 k-rows per thread (32 groups cover 64)
    int nb = (tid & 15) * 4;        // 4 n-cols per thread (16 groups cover 64)
    const float* pg = gbase + (size_t)k0i * ldb + nb;
    const float* pu = ubase + (size_t)k0i * ldb + nb;

    f32x4 zero = {0.f, 0.f, 0.f, 0.f};
    f32x4 accg[2][4], accu[2][4];
#pragma unroll
    for (int i = 0; i < 2; i++)
#pragma unroll
        for (int j = 0; j < 4; j++) { accg[i][j] = zero; accu[i][j] = zero; }

    const int NT = H_DIM / BK;   // 32
    f32x4 qg0, qg1, qu0, qu1;

#define G1_QLOAD(t_) { size_t ko_ = (size_t)(t_) * BK * ldb; \
        qg0 = *reinterpret_cast<const f32x4*>(pg + ko_); \
        qg1 = *reinterpret_cast<const f32x4*>(pg + ko_ + ldb); \
        qu0 = *reinterpret_cast<const f32x4*>(pu + ko_); \
        qu1 = *reinterpret_cast<const f32x4*>(pu + ko_ + ldb); }
#define G1_BWRITE() { _Pragma("unroll") \
        for (int i_ = 0; i_ < 4; i_++) { int n_ = nb + i_; \
            unsigned og_ = (unsigned)f2bs(qg0[i_]) | ((unsigned)f2bs(qg1[i_]) << 16); \
            unsigned ou_ = (unsigned)f2bs(qu0[i_]) | ((unsigned)f2bs(qu1[i_]) << 16); \
            int ob_ = (n_ * 128 + k0i * 2) ^ BSWZ(n_); \
            *reinterpret_cast<unsigned*>((char*)Bg + ob_) = og_; \
            *reinterpret_cast<unsigned*>((char*)Bu + ob_) = ou_; } }
#define G1_AGLL(t_, buf_) { _Pragma("unroll") \
        for (int j_ = 0; j_ < 4; j_++) \
            GLL(Abase + aoff[j_] + (unsigned)(t_) * BK, \
                &As[buf_][(wave * 32 + j_ * 8) * BK]); }

    // prologue: B(0)->LDS, A(0)->As[0], A(1)->As[1], B(1)->regs
    G1_QLOAD(0);
    G1_AGLL(0, 0);
    asm volatile("s_waitcnt vmcnt(0)" ::: "memory");
    G1_BWRITE();
    G1_AGLL(1, 1);
    G1_QLOAD(1);
    BARRIER();

    for (int t = 0; t < NT; ++t) {
        const unsigned short* Ab = &As[t & 1][0];
#pragma unroll
        for (int s = 0; s < 2; s++) {
            bf16x8 a0 = aload(Ab, wave * 32 + 0 * 16 + ln, s, h);
            bf16x8 a1 = aload(Ab, wave * 32 + 1 * 16 + ln, s, h);
#pragma unroll
            for (int j = 0; j < 4; j++) {
                bf16x8 bg = bload(Bg, j * 16 + ln, s, h);
                accg[0][j] = MFMA16(a0, bg, accg[0][j]);
                accg[1][j] = MFMA16(a1, bg, accg[1][j]);
            }
#pragma unroll
            for (int j = 0; j < 4; j++) {
                bf16x8 bu = bload(Bu, j * 16 + ln, s, h);
                accu[0][j] = MFMA16(a0, bu, accu[0][j]);
                accu[1][j] = MFMA16(a1, bu, accu[1][j]);
            }
        }
        BARRIER();                       // reads of As[t&1], B(t) done
        if (t + 1 < NT) {
            G1_BWRITE();                 // B(t+1); implicit vmcnt drain (R9 semantics)
            int tc = t + 2; if (tc > NT - 1) tc = NT - 1;
            G1_AGLL(tc, t & 1);          // A(t+2) into the buffer just read
            G1_QLOAD(tc);                // B(t+2) -> regs, stays in flight
            BARRIER();                   // B(t+1) visible; loads NOT drained
        }
    }

    int hbase = (g < E_NUM) ? rowbase : T_TOK;
#pragma unroll
    for (int i = 0; i < 2; i++) {
#pragma unroll
        for (int j = 0; j < 4; j++) {
#pragma unroll
            for (int r = 0; r < 4; r++) {
                int row = wave * 32 + i * 16 + h * 4 + r;
                int sr = mstart + row;
                if (sr < ng) {
                    float gv = accg[i][j][r], uv = accu[i][j][r];
                    float hv = gv / (1.f + expf(-gv)) * uv;  // silu(g)*u
                    int col = n0 + j * 16 + ln;
                    hmid[(size_t)(hbase + sr) * I_DIM + col] = f2bs(hv);
                }
            }
        }
    }
}

// ---------------- GEMM2: R9 schedule, 512 thr. ADD=0 shared writes, ADD=1 routed +=
// BM=256, BN=64, BK=64, 72 KB LDS. grid.x = H/64. ADD=0: grid.y=mt(0..7); ADD=1: g*8+mt
template <int ADD>
__global__ __launch_bounds__(512, 4) void gemm2_kernel(
    const unsigned short* __restrict__ hmid, const float* __restrict__ dwn,
    const float* __restrict__ sd, const int* __restrict__ perm,
    const int* __restrict__ off, float* __restrict__ out) {
    int nt = blockIdx.x;
    int g, mt, rowbase, ng, hbase;
    if (ADD) {
        g = blockIdx.y >> 3; mt = blockIdx.y & 7;
        rowbase = off[g]; ng = off[g + 1] - rowbase; hbase = rowbase;
    } else {
        g = E_NUM; mt = blockIdx.y; rowbase = 0; ng = T_TOK; hbase = T_TOK;
    }
    int mstart = mt * BM;
    if (mstart >= ng) return;

    __shared__ unsigned short As[2][BM * BK];  // 2 x 32 KB
    __shared__ unsigned short Bs[BN * BK];     // 8 KB

    int tid = threadIdx.x;
    int wave = tid >> 6, lane = tid & 63;
    int h = lane >> 4, ln = lane & 15;

    unsigned int aoff[4];
#pragma unroll
    for (int j = 0; j < 4; j++) {
        int r = wave * 32 + j * 8 + (lane >> 3);
        int sr = mstart + r; sr = (sr < ng) ? sr : (ng - 1);
        aoff[j] = (unsigned int)(hbase + sr) * I_DIM + A_SRC_CHUNK(lane);
    }
    int n0 = nt * BN;
    const float* bbase = ADD ? (dwn + (size_t)g * I_DIM * H_DIM + n0) : (sd + n0);
    const size_t ldb = H_DIM;
    int k0i = (tid >> 4) * 2;
    int nb = (tid & 15) * 4;
    const float* pb = bbase + (size_t)k0i * ldb + nb;

    f32x4 zero = {0.f, 0.f, 0.f, 0.f};
    f32x4 acc[2][4];
#pragma unroll
    for (int i = 0; i < 2; i++)
#pragma unroll
        for (int j = 0; j < 4; j++) acc[i][j] = zero;

    const int NT2 = I_DIM / BK;  // 64
    f32x4 qb0, qb1;

#define G2_QLOAD(t_) { size_t ko_ = (size_t)(t_) * BK * ldb; \
        qb0 = *reinterpret_cast<const f32x4*>(pb + ko_); \
        qb1 = *reinterpret_cast<const f32x4*>(pb + ko_ + ldb); }
#define G2_BWRITE() { _Pragma("unroll") \
        for (int i_ = 0; i_ < 4; i_++) { int n_ = nb + i_; \
            unsigned o_ = (unsigned)f2bs(qb0[i_]) | ((unsigned)f2bs(qb1[i_]) << 16); \
            int ob_ = (n_ * 128 + k0i * 2) ^ BSWZ(n_); \
            *reinterpret_cast<unsigned*>((char*)Bs + ob_) = o_; } }
#define G2_AGLL(t_, buf_) { _Pragma("unroll") \
        for (int j_ = 0; j_ < 4; j_++) \
            GLL(hmid + aoff[j_] + (unsigned)(t_) * BK, \
                &As[buf_][(wave * 32 + j_ * 8) * BK]); }

    G2_QLOAD(0);
    G2_AGLL(0, 0);
    asm volatile("s_waitcnt vmcnt(0)" ::: "memory");
    G2_BWRITE();
    G2_AGLL(1, 1);
    G2_QLOAD(1);
    BARRIER();

    for (int t = 0; t < NT2; ++t) {
        const unsigned short* Ab = &As[t & 1][0];
#pragma unroll
        for (int s = 0; s < 2; s++) {
            bf16x8 a0 = aload(Ab, wave * 32 + 0 * 16 + ln, s, h);
            bf16x8 a1 = aload(Ab, wave * 32 + 1 * 16 + ln, s, h);
#pragma unroll
            for (int j = 0; j < 4; j++) {
                bf16x8 b = bload(Bs, j * 16 + ln, s, h);
                acc[0][j] = MFMA16(a0, b, acc[0][j]);
                acc[1][j] = MFMA16(a1, b, acc[1][j]);
            }
        }
        BARRIER();
        if (t + 1 < NT2) {
            G2_BWRITE();
            int tc = t + 2; if (tc > NT2 - 1) tc = NT2 - 1;
            G2_AGLL(tc, t & 1);
            G2_QLOAD(tc);
            BARRIER();
        }
    }

#pragma unroll
    for (int i = 0; i < 2; i++) {
#pragma unroll
        for (int j = 0; j < 4; j++) {
#pragma unroll
            for (int r = 0; r < 4; r++) {
                int row = wave * 32 + i * 16 + h * 4 + r;
                int sr = mstart + row;
                if (sr < ng) {
                    int tok = ADD ? perm[rowbase + sr] : sr;
                    int col = n0 + j * 16 + ln;
                    float v = acc[i][j][r];
                    float* o = out + (size_t)tok * H_DIM + col;
                    if (ADD) *o += v; else *o = v;
                }
            }
        }
    }
}

extern "C" void kernel_launch(void* const* d_in, const int* in_sizes, int n_in,
                              void* d_out, int out_size, void* d_ws, size_t ws_size,
                              hipStream_t stream) {
    (void)in_sizes; (void)n_in; (void)out_size;
    const float* hs  = (const float*)d_in[0];
    const float* rw  = (const float*)d_in[1];
    const float* gup = (const float*)d_in[2];
    const float* dwn = (const float*)d_in[3];
    const float* sg  = (const float*)d_in[4];
    const float* su  = (const float*)d_in[5];
    const float* sd  = (const float*)d_in[6];
    float* out = (float*)d_out;
    float* out_scores = out + (size_t)T_TOK * H_DIM;

    char* w = (char*)d_ws;
    size_t o = 0;
    auto alloc = [&](size_t bytes) {
        void* p = w + o;
        o += (bytes + 255) & ~(size_t)255;
        return p;
    };
    unsigned short* xb   = (unsigned short*)alloc((size_t)T_TOK * H_DIM * 2);
    unsigned short* xs   = (unsigned short*)alloc((size_t)T_TOK * H_DIM * 2);
    unsigned short* hmid = (unsigned short*)alloc((size_t)2 * T_TOK * I_DIM * 2);
    int* eidx    = (int*)alloc(T_TOK * 4);
    int* perm    = (int*)alloc(T_TOK * 4);
    int* off     = (int*)alloc(64 * 4);
    if (ws_size < o) return;  // insufficient workspace

    router_convert_kernel<<<T_TOK / 4, 256, 0, stream>>>(hs, rw, out_scores, eidx, xb, xs);
    group_kernel<<<1, 256, 0, stream>>>(eidx, perm, off);

    gemm1_kernel<<<dim3(I_DIM / BN, 9 * 8), 512, 0, stream>>>(
        xb, xs, gup, sg, su, perm, off, hmid);
    gemm2_kernel<0><<<dim3(H_DIM / BN, 8), 512, 0, stream>>>(hmid, dwn, sd, perm, off, out);
    gemm2_kernel<1><<<dim3(H_DIM / BN, E_NUM * 8), 512, 0, stream>>>(hmid, dwn, sd, perm, off, out);
}